// Round 20
// baseline (317.558 us; speedup 1.0000x reference)
//
#include <hip/hip_runtime.h>
#include <hip/hip_bf16.h>

// ============================================================================
// FrameAggregator — ROUND 20:
//  * q_lvl2: 512 threads (8 waves) — double per-CU wave residency at grid=128.
// Everything else identical to the round-19 passing pipeline.
// ============================================================================

typedef __hip_bfloat16 bf16;
#define DEV static __device__ __forceinline__
DEV float b2f(bf16 x){ return __bfloat162float(x); }
DEV bf16  f2b(float x){ return __float2bfloat16(x); }

constexpr int B_  = 128;
constexpr int N_  = 512;
constexpr int EG_ = 8192;
constexpr int E_  = B_*EG_;     // 1048576
constexpr int NT_ = B_*N_;      // 65536

constexpr size_t OFF_MC  = (size_t)B_*32*128;                 // 524288
constexpr size_t OFF_O   = OFF_MC + 1;
constexpr size_t OFF_AGG = OFF_O + 1;                         // 524290
constexpr size_t OFF_ADJ = OFF_AGG + (size_t)B_*N_*32;        // 2621442

constexpr size_t PHALF = (size_t)B_*4096;                     // partial stride

// ---------------------------------------------------------------------------
__global__ void q_init(float* den, float* losses){
  int i = threadIdx.x;
  if (i < B_) den[i] = 0.f;
  if (i < 2)  losses[i] = 0.f;
}
__global__ void q_sent(float* out, float v){
  if (threadIdx.x == 0) out[0] = v;
}

// ---------------------------------------------------------------------------
// deg/drow via LDS scatter: block per graph.
__global__ __launch_bounds__(256) void q_deg(const int* __restrict__ ei,
    const float* __restrict__ ea, float* __restrict__ dis, float* __restrict__ drow){
  __shared__ float degL[N_];
  __shared__ float drL[N_];
  int t = threadIdx.x, b = blockIdx.x, base = b*N_;
  for (int j=t; j<N_; j+=256){ degL[j] = 1.0f; drL[j] = 0.f; }  // 1.0 = self loop
  __syncthreads();
  int e0 = b*EG_;
  for (int j=t; j<EG_; j+=256){
    int e = e0 + j;
    int r = ei[e], c = ei[E_+e];
    atomicAdd(&degL[c-base], ea[e]);
    atomicAdd(&drL [r-base], 1.0f);
  }
  __syncthreads();
  for (int j=t; j<N_; j+=256){
    dis [base+j] = rsqrtf(degL[j]);
    drow[base+j] = drL[j];
  }
}

// ---------------------------------------------------------------------------
// q_csr: per-graph CSR build. by-col: (csrR, csrW=dis[r]*ea*dis[c]); by-row: csrC.
__global__ __launch_bounds__(256) void q_csr(const int* __restrict__ ei,
    const float* __restrict__ ea, const float* __restrict__ dis,
    int* __restrict__ offC, int* __restrict__ offR,
    int* __restrict__ csrR, float* __restrict__ csrW, int* __restrict__ csrC){
  __shared__ int cC[N_], cR[N_];
  int t = threadIdx.x, b = blockIdx.x, base = b*N_, e0 = b*EG_;
  for (int j=t; j<N_; j+=256){ cC[j]=0; cR[j]=0; }
  __syncthreads();
  for (int j=t; j<EG_; j+=256){
    int e = e0 + j;
    atomicAdd(&cC[ei[E_+e]-base], 1);
    atomicAdd(&cR[ei[e]   -base], 1);
  }
  __syncthreads();
  if (t == 0){
    int aC = 0, aR = 0;
    for (int n=0; n<N_; ++n){
      int vc = cC[n], vr = cR[n];
      cC[n] = aC; cR[n] = aR;
      aC += vc; aR += vr;
    }
  }
  __syncthreads();
  for (int j=t; j<N_; j+=256){ offC[base+j] = e0 + cC[j]; offR[base+j] = e0 + cR[j]; }
  __syncthreads();
  for (int j=t; j<EG_; j+=256){
    int e = e0 + j;
    int r = ei[e], c = ei[E_+e];
    float w = dis[r]*ea[e]*dis[c];
    int p  = atomicAdd(&cC[c-base], 1);
    csrR[e0+p] = r;  csrW[e0+p] = w;
    int p2 = atomicAdd(&cR[r-base], 1);
    csrC[e0+p2] = c;
  }
}

// ---------------------------------------------------------------------------
// xw = pos @ W1: 64-node tiles, LDS-staged pos+W1, 4x4 register tiles.
__global__ __launch_bounds__(256) void q_xw(const float* __restrict__ pos,
    const float* __restrict__ W1, bf16* __restrict__ xw){
  __shared__ float pL[64][129];
  __shared__ float wT[128][64];
  int t = threadIdx.x;
  int n0 = blockIdx.x*64;
  for (int j=t; j<2048; j+=256){
    int n = j >> 5, c4 = j & 31;
    float4 v = *reinterpret_cast<const float4*>(pos + (size_t)(n0+n)*128 + c4*4);
    pL[n][c4*4+0]=v.x; pL[n][c4*4+1]=v.y; pL[n][c4*4+2]=v.z; pL[n][c4*4+3]=v.w;
  }
  for (int j=t; j<8192; j+=256) ((float*)wT)[j] = W1[j];
  __syncthreads();
  int ti = t>>4, tj = t&15;
  float acc[4][4];
  #pragma unroll
  for (int i=0;i<4;i++)
    #pragma unroll
    for (int j=0;j<4;j++) acc[i][j] = 0.f;
  for (int k=0; k<128; ++k){
    float xs[4], ws[4];
    #pragma unroll
    for (int i=0;i<4;i++) xs[i] = pL[ti*4+i][k];
    #pragma unroll
    for (int j=0;j<4;j++) ws[j] = wT[k][tj*4+j];
    #pragma unroll
    for (int i=0;i<4;i++)
      #pragma unroll
      for (int j=0;j<4;j++) acc[i][j] += xs[i]*ws[j];
  }
  #pragma unroll
  for (int i=0;i<4;i++)
    #pragma unroll
    for (int j=0;j<4;j++)
      xw[(size_t)(n0+ti*4+i)*64 + tj*4+j] = f2b(acc[i][j]);
}

// ---------------------------------------------------------------------------
// GCN conv: one wave per destination node, CSR gather, 4x unrolled.
__global__ __launch_bounds__(256) void q_gcn(const int* __restrict__ offC,
    const int* __restrict__ csrR, const float* __restrict__ csrW,
    const float* __restrict__ dis, const bf16* __restrict__ xw,
    const float* __restrict__ b1, bf16* __restrict__ x1){
  int n = (blockIdx.x*256 + threadIdx.x) >> 6;
  int f = threadIdx.x & 63;
  float d = dis[n];
  float h = d*d*b2f(xw[(size_t)n*64 + f]);
  int s = offC[n];
  int e = ((n & 511) == 511) ? ((n >> 9) + 1)*EG_ : offC[n+1];
  int j = s;
  for (; j + 3 < e; j += 4){
    int r0 = csrR[j],   r1 = csrR[j+1], r2 = csrR[j+2], r3 = csrR[j+3];
    float w0 = csrW[j], w1 = csrW[j+1], w2 = csrW[j+2], w3 = csrW[j+3];
    float v0 = b2f(xw[(size_t)r0*64 + f]);
    float v1 = b2f(xw[(size_t)r1*64 + f]);
    float v2 = b2f(xw[(size_t)r2*64 + f]);
    float v3 = b2f(xw[(size_t)r3*64 + f]);
    h += w0*v0 + w1*v1 + w2*v2 + w3*v3;
  }
  for (; j < e; ++j) h += csrW[j] * b2f(xw[(size_t)csrR[j]*64 + f]);
  h += b1[f];
  x1[(size_t)n*64 + f] = f2b(h > 0.f ? h : 0.f);
}

// ---------------------------------------------------------------------------
// s1 = softmax(x1 @ Wp1 + bp1): 64 nodes/block, register-tile GEMM.
__global__ __launch_bounds__(256) void q_s1(const bf16* __restrict__ x1,
    const float* __restrict__ Wp1, const float* __restrict__ bp1,
    const float* __restrict__ drow, bf16* __restrict__ s1, float* __restrict__ den){
  __shared__ float xT[64][65];
  __shared__ float wT[64][64];
  __shared__ float denL;
  int t = threadIdx.x;
  int n0 = blockIdx.x*64;
  if (t == 0) denL = 0.f;
  for (int j=t; j<4096; j+=256){
    wT[j>>6][j&63] = Wp1[j];
    xT[j>>6][j&63] = b2f(x1[(size_t)n0*64 + j]);
  }
  __syncthreads();
  int ti = t>>4, tj = t&15;
  float acc[4][4];
  #pragma unroll
  for (int i=0;i<4;i++)
    #pragma unroll
    for (int j=0;j<4;j++) acc[i][j] = 0.f;
  for (int f=0; f<64; ++f){
    float xs[4], ws[4];
    #pragma unroll
    for (int i=0;i<4;i++) xs[i] = xT[ti*4+i][f];
    #pragma unroll
    for (int j=0;j<4;j++) ws[j] = wT[f][tj*4+j];
    #pragma unroll
    for (int i=0;i<4;i++)
      #pragma unroll
      for (int j=0;j<4;j++) acc[i][j] += xs[i]*ws[j];
  }
  {
    float bp[4];
    #pragma unroll
    for (int j=0;j<4;j++) bp[j] = bp1[tj*4+j];
    #pragma unroll
    for (int i=0;i<4;i++)
      #pragma unroll
      for (int j=0;j<4;j++) acc[i][j] += bp[j];
  }
  #pragma unroll
  for (int i=0;i<4;i++){
    float m = fmaxf(fmaxf(acc[i][0],acc[i][1]), fmaxf(acc[i][2],acc[i][3]));
    #pragma unroll
    for (int o=8;o>=1;o>>=1) m = fmaxf(m, __shfl_xor(m, o));
    float e[4]; float ssum = 0.f;
    #pragma unroll
    for (int j=0;j<4;j++){ e[j] = expf(acc[i][j]-m); ssum += e[j]; }
    #pragma unroll
    for (int o=8;o>=1;o>>=1) ssum += __shfl_xor(ssum, o);
    float inv = 1.f/ssum, q = 0.f;
    int n = n0 + ti*4 + i;
    #pragma unroll
    for (int j=0;j<4;j++){
      float sv = e[j]*inv;
      s1[(size_t)n*64 + tj*4 + j] = f2b(sv);
      q += sv*sv;
    }
    #pragma unroll
    for (int o=8;o>=1;o>>=1) q += __shfl_xor(q, o);
    if (tj == 0) atomicAdd(&denL, q * drow[n]);
  }
  __syncthreads();
  if (t == 0) atomicAdd(&den[n0 >> 9], denL);
}

// ---------------------------------------------------------------------------
// U = A @ s1: one wave per row node, CSR(by-row) gather, 4x unrolled.
__global__ __launch_bounds__(256) void q_u(const int* __restrict__ offR,
    const int* __restrict__ csrC, const bf16* __restrict__ s1,
    bf16* __restrict__ U){
  int n = (blockIdx.x*256 + threadIdx.x) >> 6;
  int l = threadIdx.x & 63;
  float u = 0.f;
  int s = offR[n];
  int e = ((n & 511) == 511) ? ((n >> 9) + 1)*EG_ : offR[n+1];
  int j = s;
  for (; j + 3 < e; j += 4){
    int c0 = csrC[j], c1 = csrC[j+1], c2 = csrC[j+2], c3 = csrC[j+3];
    float v0 = b2f(s1[(size_t)c0*64 + l]);
    float v1 = b2f(s1[(size_t)c1*64 + l]);
    float v2 = b2f(s1[(size_t)c2*64 + l]);
    float v3 = b2f(s1[(size_t)c3*64 + l]);
    u += v0 + v1 + v2 + v3;
  }
  for (; j < e; ++j) u += b2f(s1[(size_t)csrC[j]*64 + l]);
  U[(size_t)n*64 + l] = f2b(u);
}

// ---------------------------------------------------------------------------
// q_p3: K-split x2, plain stores into partial buffers p[half].
__global__ __launch_bounds__(256) void q_p3(const bf16* __restrict__ s1,
    const bf16* __restrict__ U, const bf16* __restrict__ x1,
    float* __restrict__ adjPp, float* __restrict__ ssPp, float* __restrict__ X1pp){
  __shared__ float sL[64][64];
  __shared__ float uL[64][64];
  __shared__ float xL[64][64];
  int t = threadIdx.x, blk = blockIdx.x;
  int b = blk >> 1, half = blk & 1;
  int base = b*N_ + half*256;
  int ti = t>>4, tj = t&15;
  float accA[4][4], accS[4][4], accX[4][4];
  #pragma unroll
  for (int i=0;i<4;i++)
    #pragma unroll
    for (int j=0;j<4;j++){ accA[i][j]=0.f; accS[i][j]=0.f; accX[i][j]=0.f; }
  for (int c=0; c<4; ++c){
    __syncthreads();
    for (int j=t; j<4096; j+=256){
      int n = j>>6, q = j&63;
      size_t g = (size_t)(base + c*64 + n)*64 + q;
      sL[n][q] = b2f(s1[g]);
      uL[n][q] = b2f(U [g]);
      xL[n][q] = b2f(x1[g]);
    }
    __syncthreads();
    for (int n=0; n<64; ++n){
      float4 skv = *reinterpret_cast<const float4*>(&sL[n][ti*4]);
      float4 ulv = *reinterpret_cast<const float4*>(&uL[n][tj*4]);
      float4 xlv = *reinterpret_cast<const float4*>(&xL[n][tj*4]);
      float4 slv = *reinterpret_cast<const float4*>(&sL[n][tj*4]);
      float sk[4] = {skv.x, skv.y, skv.z, skv.w};
      float ul[4] = {ulv.x, ulv.y, ulv.z, ulv.w};
      float xl[4] = {xlv.x, xlv.y, xlv.z, xlv.w};
      float sl[4] = {slv.x, slv.y, slv.z, slv.w};
      #pragma unroll
      for (int i=0;i<4;i++)
        #pragma unroll
        for (int j=0;j<4;j++){
          accA[i][j] += sk[i]*ul[j];
          accS[i][j] += sk[i]*sl[j];
          accX[i][j] += sk[i]*xl[j];
        }
    }
  }
  size_t pb = (size_t)half*PHALF + (size_t)b*4096;
  #pragma unroll
  for (int i=0;i<4;i++)
    #pragma unroll
    for (int j=0;j<4;j++){
      size_t o = pb + (ti*4+i)*64 + tj*4+j;
      adjPp[o] = accA[i][j];
      ssPp [o] = accS[i][j];
      X1pp [o] = accX[i][j];
    }
}

// ---------------------------------------------------------------------------
// norm1: sums partials (adjP/ssP in LDS, X1p -> X1n); losses; A2 = degnorm.
__global__ __launch_bounds__(256) void q_norm1(const float* __restrict__ adjPp,
    const float* __restrict__ ssPp, const float* __restrict__ X1pp,
    const float* __restrict__ den, float* __restrict__ A2,
    float* __restrict__ X1n, float* __restrict__ losses){
  __shared__ float aL[4096];
  __shared__ float sL[4096];
  __shared__ float rL[64];
  __shared__ float red[4];
  int b = blockIdx.x, t = threadIdx.x;
  size_t pb = (size_t)b*4096;
  for (int j = t; j < 4096; j += 256){
    aL[j] = adjPp[pb + j] + adjPp[PHALF + pb + j];
    sL[j] = ssPp [pb + j] + ssPp [PHALF + pb + j];
    X1n[pb + j] = X1pp[pb + j] + X1pp[PHALF + pb + j];
  }
  __syncthreads();
  if (t == 0){
    float tr = 0.f;
    for (int k = 0; k < 64; ++k) tr += aL[k*64 + k];
    atomicAdd(&losses[0], -(tr/den[b]) * (1.0f/B_));
  }
  if (t < 64){
    float rs = 0.f;
    for (int l = 0; l < 64; ++l) rs += aL[t*64 + l];
    rs -= aL[t*64 + t];
    rL[t] = 1.f/(sqrtf(rs) + 1e-15f);
  }
  float pp = 0.f;
  for (int j = t; j < 4096; j += 256){ float v = sL[j]; pp += v*v; }
  #pragma unroll
  for (int o = 32; o >= 1; o >>= 1) pp += __shfl_xor(pp, o);
  if ((t & 63) == 0) red[t >> 6] = pp;
  __syncthreads();
  float fro = sqrtf(red[0]+red[1]+red[2]+red[3]);
  __syncthreads();
  float op = 0.f;
  for (int j = t; j < 4096; j += 256){
    int kk = j >> 6, ll = j & 63;
    float v = sL[j]/fro - ((kk==ll) ? 0.125f : 0.f);
    op += v*v;
  }
  #pragma unroll
  for (int o = 32; o >= 1; o >>= 1) op += __shfl_xor(op, o);
  if ((t & 63) == 0) red[t >> 6] = op;
  __syncthreads();
  if (t == 0) atomicAdd(&losses[1], sqrtf(red[0]+red[1]+red[2]+red[3]) * (1.0f/B_));
  for (int j = t; j < 4096; j += 256){
    int kk = j >> 6, ll = j & 63;
    A2[(size_t)b*4096 + j] = (kk==ll) ? 0.f : aL[j]*rL[kk]*rL[ll];
  }
}

// ---------------------------------------------------------------------------
// q_lvl2: FUSED level-2 GCN + pool2 + level-3 GCN per graph. 512 threads.
__global__ __launch_bounds__(512) void q_lvl2(const float* __restrict__ X1p,
    const float* __restrict__ A2g,
    const float* __restrict__ W2r, const float* __restrict__ b2,
    const float* __restrict__ W2s, const float* __restrict__ Wp2,
    const float* __restrict__ bp2, const float* __restrict__ W3r,
    const float* __restrict__ b3, const float* __restrict__ W3s,
    float* __restrict__ s2f, float* __restrict__ out, float* __restrict__ losses){
  __shared__ float XL[64][64], AL[64][64], AXL[64][64], x2L[64][64];
  __shared__ float s2L[64][32], VL[64][32];
  __shared__ float adj2L[32][32], ss2L[32][32], A3L[32][32];
  __shared__ float o2L[32][64], GL[32][64];
  __shared__ float wp2L[64][32];
  __shared__ float r2L[32], red[8];
  __shared__ float den2s;
  int t = threadIdx.x, b = blockIdx.x;
  int wv = t>>6, lane = t&63;          // 8 waves
  for (int j=t; j<4096; j+=512){
    ((float*)XL)[j] = X1p[(size_t)b*4096 + j];
    ((float*)AL)[j] = A2g[(size_t)b*4096 + j];
  }
  for (int j=t; j<2048; j+=512) ((float*)wp2L)[j] = Wp2[j];
  __syncthreads();
  // AX = A2 @ X1p  (8 rows per wave)
  for (int i=0;i<8;i++){
    int n = wv*8+i; float a = 0.f;
    for (int m=0;m<64;m++) a += AL[n][m]*XL[m][lane];
    AXL[n][lane] = a;
  }
  __syncthreads();
  // x2 = relu(AX@W2r + X1p@W2s + b2)
  {
    float bb = b2[lane];
    for (int i=0;i<8;i++){
      int n = wv*8+i; float a = bb;
      for (int m=0;m<64;m++) a += AXL[n][m]*W2r[m*64+lane];
      for (int m=0;m<64;m++) a += XL[n][m]*W2s[m*64+lane];
      x2L[n][lane] = a > 0.f ? a : 0.f;
    }
  }
  __syncthreads();
  // s2 = softmax(x2@Wp2 + bp2) over 32 (duplicated 32-lane halves)
  {
    int k = lane & 31;
    for (int i=0;i<8;i++){
      int n = wv*8+i;
      float lgv = bp2[k];
      for (int f=0; f<64; f++) lgv += x2L[n][f]*wp2L[f][k];
      float m = lgv;
      #pragma unroll
      for (int o=16;o>=1;o>>=1) m = fmaxf(m, __shfl_xor(m, o));
      float p = expf(lgv - m), ssum = p;
      #pragma unroll
      for (int o=16;o>=1;o>>=1) ssum += __shfl_xor(ssum, o);
      float sv = p/ssum;
      s2L[n][k] = sv;
      s2f[(size_t)b*2048 + n*32 + k] = sv;
    }
  }
  __syncthreads();
  // den2 = sum_n ||s2_n||^2 * rowsum(A2[n])   (wave 0)
  {
    float part = 0.f;
    if (t < 64){
      float rs = 0.f; for (int m=0;m<64;m++) rs += AL[t][m];
      float q  = 0.f; for (int k2=0;k2<32;k2++){ float s = s2L[t][k2]; q += s*s; }
      part = q*rs;
    }
    #pragma unroll
    for (int o=32;o>=1;o>>=1) part += __shfl_xor(part, o);
    if (t == 0) den2s = part;
  }
  __syncthreads();
  // V = A2 @ s2
  for (int j=0;j<4;j++){
    int idx = t + 512*j; int n = idx>>5, l = idx&31;
    float a = 0.f;
    for (int m=0;m<64;m++) a += AL[n][m]*s2L[m][l];
    VL[n][l] = a;
  }
  __syncthreads();
  // adj2 = s2^T V ; ss2 = s2^T s2
  for (int j=0;j<2;j++){
    int idx = t + 512*j; int k2 = idx>>5, l = idx&31;
    float a = 0.f, c2 = 0.f;
    for (int n=0;n<64;n++){ float s = s2L[n][k2]; a += s*VL[n][l]; c2 += s*s2L[n][l]; }
    adj2L[k2][l] = a; ss2L[k2][l] = c2;
  }
  __syncthreads();
  if (t == 0){
    float tr = 0.f; for (int k2=0;k2<32;k2++) tr += adj2L[k2][k2];
    atomicAdd(&losses[0], -(tr/den2s) * (1.0f/B_));
  }
  if (t < 32){
    float rs = 0.f; for (int l=0;l<32;l++) rs += adj2L[t][l];
    rs -= adj2L[t][t];
    r2L[t] = 1.f/(sqrtf(rs) + 1e-15f);
  }
  // fro2 / ortho2 (8-wave reduction)
  {
    float pp = 0.f;
    for (int j=t; j<1024; j+=512){ float v = ((float*)ss2L)[j]; pp += v*v; }
    #pragma unroll
    for (int o=32;o>=1;o>>=1) pp += __shfl_xor(pp, o);
    if ((t & 63) == 0) red[t >> 6] = pp;
    __syncthreads();
    float fro = sqrtf(red[0]+red[1]+red[2]+red[3]+red[4]+red[5]+red[6]+red[7]);
    __syncthreads();
    float op = 0.f;
    for (int j=t; j<1024; j+=512){
      int k2 = j>>5, l = j&31;
      float v = ((float*)ss2L)[j]/fro - ((k2==l) ? 0.1767766952966369f : 0.f);
      op += v*v;
    }
    #pragma unroll
    for (int o=32;o>=1;o>>=1) op += __shfl_xor(op, o);
    if ((t & 63) == 0) red[t >> 6] = op;
    __syncthreads();
    if (t == 0) atomicAdd(&losses[1],
      sqrtf(red[0]+red[1]+red[2]+red[3]+red[4]+red[5]+red[6]+red[7]) * (1.0f/B_));
  }
  __syncthreads();
  // A3 -> out adj
  for (int j=0;j<2;j++){
    int idx = t + 512*j; int k2 = idx>>5, l = idx&31;
    float v = (k2==l) ? 0.f : adj2L[k2][l]*r2L[k2]*r2L[l];
    A3L[k2][l] = v;
    out[OFF_ADJ + (size_t)b*1024 + idx] = v;
  }
  __syncthreads();
  // o2 = s2^T x2
  for (int j=0;j<4;j++){
    int idx = t + 512*j; int k2 = idx>>6, f = idx&63;
    float a = 0.f;
    for (int n=0;n<64;n++) a += s2L[n][k2]*x2L[n][f];
    o2L[k2][f] = a;
  }
  __syncthreads();
  // G = A3 @ o2
  for (int j=0;j<4;j++){
    int idx = t + 512*j; int n = idx>>6, f = idx&63;
    float a = 0.f;
    for (int m=0;m<32;m++) a += A3L[n][m]*o2L[m][f];
    GL[n][f] = a;
  }
  __syncthreads();
  // x3 = G@W3r + o2@W3s + b3 -> out x
  for (int j=0;j<8;j++){
    int idx = t + 512*j; int n = idx>>7, o = idx&127;
    float a = b3[o];
    for (int f=0;f<64;f++) a += GL[n][f]*W3r[f*128+o];
    for (int f=0;f<64;f++) a += o2L[n][f]*W3s[f*128+o];
    out[(size_t)b*4096 + idx] = a;
  }
}

// ---------------------------------------------------------------------------
// agg = s1 @ s2: 8 blocks/graph (64 nodes each), LDS-staged, 4x2 register tile.
__global__ __launch_bounds__(256) void q_agg(const bf16* __restrict__ s1,
    const float* __restrict__ s2, float* __restrict__ out){
  __shared__ float s1L[64][65];
  __shared__ float s2L[64][33];
  int t = threadIdx.x, blk = blockIdx.x;
  int b = blk >> 3, n0 = (blk & 7)*64;
  for (int j=t; j<4096; j+=256){
    int n = j>>6, k = j&63;
    s1L[n][k] = b2f(s1[((size_t)b*N_ + n0 + n)*64 + k]);
  }
  for (int j=t; j<2048; j+=256){
    int k = j>>5, l = j&31;
    s2L[k][l] = s2[(size_t)b*2048 + j];
  }
  __syncthreads();
  int ti = t>>4, tj = t&15;
  float acc[4][2];
  #pragma unroll
  for (int i=0;i<4;i++){ acc[i][0]=0.f; acc[i][1]=0.f; }
  for (int k=0; k<64; ++k){
    float xs[4];
    #pragma unroll
    for (int i=0;i<4;i++) xs[i] = s1L[ti*4+i][k];
    float w0 = s2L[k][tj*2], w1 = s2L[k][tj*2+1];
    #pragma unroll
    for (int i=0;i<4;i++){ acc[i][0] += xs[i]*w0; acc[i][1] += xs[i]*w1; }
  }
  #pragma unroll
  for (int i=0;i<4;i++){
    size_t o = OFF_AGG + ((size_t)b*N_ + n0 + ti*4+i)*32 + tj*2;
    out[o]   = acc[i][0];
    out[o+1] = acc[i][1];
  }
}

// ---------------------------------------------------------------------------
__global__ void q_loss(const float* losses, float* out){
  if (threadIdx.x == 0){
    out[OFF_MC] = losses[0];
    out[OFF_O]  = losses[1];
  }
}

// ===========================================================================
extern "C" void kernel_launch(void* const* d_in, const int* in_sizes, int n_in,
                              void* d_out, int out_size, void* d_ws, size_t ws_size,
                              hipStream_t stream){
  (void)out_size;
  float* out = (float*)d_out;

  static const long long EXP_SIZES[16] = {
    8388608LL, 2097152LL, 1048576LL, 65536LL,
    8192LL, 64LL, 4096LL, 64LL,
    4096LL, 64LL, 4096LL, 2048LL, 32LL,
    8192LL, 128LL, 8192LL };
  if (n_in != 16){ q_sent<<<1,64,0,stream>>>(out, exp2f(36.f)); return; }
  for (int i = 0; i < 16; ++i){
    if ((long long)in_sizes[i] != EXP_SIZES[i]){
      q_sent<<<1,64,0,stream>>>(out, exp2f((float)(37+i))); return;
    }
  }

  const float* pos = (const float*)d_in[0];
  const int*   ei  = (const int*)  d_in[1];
  const float* ea  = (const float*)d_in[2];
  const float* W1  = (const float*)d_in[4];
  const float* b1  = (const float*)d_in[5];
  const float* Wp1 = (const float*)d_in[6];
  const float* bp1 = (const float*)d_in[7];
  const float* W2r = (const float*)d_in[8];
  const float* b2  = (const float*)d_in[9];
  const float* W2s = (const float*)d_in[10];
  const float* Wp2 = (const float*)d_in[11];
  const float* bp2 = (const float*)d_in[12];
  const float* W3r = (const float*)d_in[13];
  const float* b3  = (const float*)d_in[14];
  const float* W3s = (const float*)d_in[15];

  // ---- workspace (~42.1 MB) with lifetime-safe unions
  constexpr size_t MB2 = (size_t)B_*4096*4;     // 2 MB
  char* w = (char*)d_ws;
  float* dis    = (float*)w; w += (size_t)NT_*4;
  float* drow   = (float*)w; w += (size_t)NT_*4;
  float* den    = (float*)w; w += (size_t)B_*4;
  float* losses = (float*)w; w += 64;
  int*   offC   = (int*)  w; w += (size_t)NT_*4;
  int*   offR   = (int*)  w; w += (size_t)NT_*4;
  char*  R1     = w;         w += 2*MB2;
  char*  R2     = w;         w += 2*MB2;
  char*  R3     = w;         w += 2*MB2;
  float* A2n    = (float*)w; w += MB2;
  float* X1n    = (float*)w; w += MB2;
  float* s2     = (float*)w; w += (size_t)B_*2048*4;
  bf16*  xwU    = (bf16*)w;  w += (size_t)NT_*64*2;    // xw, then U
  bf16*  x1     = (bf16*)w;  w += (size_t)NT_*64*2;
  bf16*  s1     = (bf16*)w;  w += (size_t)NT_*64*2;
  size_t need = (size_t)(w - (char*)d_ws);
  if (ws_size < need){ q_sent<<<1,64,0,stream>>>(out, exp2f(20.f)); return; }

  int*   csrR  = (int*)  R1;
  float* csrW  = (float*)R2;
  int*   csrC  = (int*)  R3;
  float* adjPp = (float*)R1;
  float* ssPp  = (float*)R2;
  float* X1pp  = (float*)R3;

  q_init <<<1,    256, 0, stream>>>(den, losses);
  q_deg  <<<B_,   256, 0, stream>>>(ei, ea, dis, drow);
  q_csr  <<<B_,   256, 0, stream>>>(ei, ea, dis, offC, offR, csrR, csrW, csrC);
  q_xw   <<<NT_/64,256, 0, stream>>>(pos, W1, xwU);
  q_gcn  <<<16384,256, 0, stream>>>(offC, csrR, csrW, dis, xwU, b1, x1);
  q_s1   <<<NT_/64,256, 0, stream>>>(x1, Wp1, bp1, drow, s1, den);
  q_u    <<<16384,256, 0, stream>>>(offR, csrC, s1, xwU);     // xwU := U
  q_p3   <<<B_*2, 256, 0, stream>>>(s1, xwU, x1, adjPp, ssPp, X1pp);
  q_norm1<<<B_,   256, 0, stream>>>(adjPp, ssPp, X1pp, den, A2n, X1n, losses);
  q_lvl2 <<<B_,   512, 0, stream>>>(X1n, A2n, W2r, b2, W2s, Wp2, bp2,
                                    W3r, b3, W3s, s2, out, losses);
  q_agg  <<<1024, 256, 0, stream>>>(s1, s2, out);
  q_loss <<<1,     64, 0, stream>>>(losses, out);
}

// Round 21
// 299.210 us; speedup vs baseline: 1.0613x; 1.0613x over previous
//
#include <hip/hip_runtime.h>
#include <hip/hip_bf16.h>

// ============================================================================
// FrameAggregator — ROUND 21:
//  * q_lvl2: 256 thr, register-tiled AX/x2/x3 (4x4 tiles, LDS traffic /4),
//    padded LDS arrays (bank-conflict-free column reads).
//  * q_degcsr: fused q_deg + q_csr (one edge pass saved).
// Everything else identical to the round-19/20 passing pipeline.
// ============================================================================

typedef __hip_bfloat16 bf16;
#define DEV static __device__ __forceinline__
DEV float b2f(bf16 x){ return __bfloat162float(x); }
DEV bf16  f2b(float x){ return __float2bfloat16(x); }

constexpr int B_  = 128;
constexpr int N_  = 512;
constexpr int EG_ = 8192;
constexpr int E_  = B_*EG_;     // 1048576
constexpr int NT_ = B_*N_;      // 65536

constexpr size_t OFF_MC  = (size_t)B_*32*128;                 // 524288
constexpr size_t OFF_O   = OFF_MC + 1;
constexpr size_t OFF_AGG = OFF_O + 1;                         // 524290
constexpr size_t OFF_ADJ = OFF_AGG + (size_t)B_*N_*32;        // 2621442

constexpr size_t PHALF = (size_t)B_*4096;                     // partial stride

// ---------------------------------------------------------------------------
__global__ void q_init(float* den, float* losses){
  int i = threadIdx.x;
  if (i < B_) den[i] = 0.f;
  if (i < 2)  losses[i] = 0.f;
}
__global__ void q_sent(float* out, float v){
  if (threadIdx.x == 0) out[0] = v;
}

// ---------------------------------------------------------------------------
// q_degcsr: FUSED deg/drow + CSR build (one edge pass for counts+degrees,
// one for scatter; dis recomputed from LDS degL in pass 2).
__global__ __launch_bounds__(256) void q_degcsr(const int* __restrict__ ei,
    const float* __restrict__ ea, float* __restrict__ dis, float* __restrict__ drow,
    int* __restrict__ offC, int* __restrict__ offR,
    int* __restrict__ csrR, float* __restrict__ csrW, int* __restrict__ csrC){
  __shared__ float degL[N_];
  __shared__ float drL[N_];
  __shared__ int cC[N_], cR[N_];
  int t = threadIdx.x, b = blockIdx.x, base = b*N_, e0 = b*EG_;
  for (int j=t; j<N_; j+=256){ degL[j]=1.0f; drL[j]=0.f; cC[j]=0; cR[j]=0; }
  __syncthreads();
  for (int j=t; j<EG_; j+=256){
    int e = e0 + j;
    int r = ei[e], c = ei[E_+e];
    atomicAdd(&degL[c-base], ea[e]);
    atomicAdd(&drL [r-base], 1.0f);
    atomicAdd(&cC[c-base], 1);
    atomicAdd(&cR[r-base], 1);
  }
  __syncthreads();
  for (int j=t; j<N_; j+=256){
    dis [base+j] = rsqrtf(degL[j]);
    drow[base+j] = drL[j];
  }
  if (t == 0){
    int aC = 0, aR = 0;
    for (int n=0; n<N_; ++n){
      int vc = cC[n], vr = cR[n];
      cC[n] = aC; cR[n] = aR;
      aC += vc; aR += vr;
    }
  }
  __syncthreads();
  for (int j=t; j<N_; j+=256){ offC[base+j] = e0 + cC[j]; offR[base+j] = e0 + cR[j]; }
  __syncthreads();
  for (int j=t; j<EG_; j+=256){
    int e = e0 + j;
    int r = ei[e], c = ei[E_+e];
    float w = rsqrtf(degL[r-base])*ea[e]*rsqrtf(degL[c-base]);
    int p  = atomicAdd(&cC[c-base], 1);
    csrR[e0+p] = r;  csrW[e0+p] = w;
    int p2 = atomicAdd(&cR[r-base], 1);
    csrC[e0+p2] = c;
  }
}

// ---------------------------------------------------------------------------
// xw = pos @ W1: 64-node tiles, LDS-staged pos+W1, 4x4 register tiles.
__global__ __launch_bounds__(256) void q_xw(const float* __restrict__ pos,
    const float* __restrict__ W1, bf16* __restrict__ xw){
  __shared__ float pL[64][129];
  __shared__ float wT[128][64];
  int t = threadIdx.x;
  int n0 = blockIdx.x*64;
  for (int j=t; j<2048; j+=256){
    int n = j >> 5, c4 = j & 31;
    float4 v = *reinterpret_cast<const float4*>(pos + (size_t)(n0+n)*128 + c4*4);
    pL[n][c4*4+0]=v.x; pL[n][c4*4+1]=v.y; pL[n][c4*4+2]=v.z; pL[n][c4*4+3]=v.w;
  }
  for (int j=t; j<8192; j+=256) ((float*)wT)[j] = W1[j];
  __syncthreads();
  int ti = t>>4, tj = t&15;
  float acc[4][4];
  #pragma unroll
  for (int i=0;i<4;i++)
    #pragma unroll
    for (int j=0;j<4;j++) acc[i][j] = 0.f;
  for (int k=0; k<128; ++k){
    float xs[4], ws[4];
    #pragma unroll
    for (int i=0;i<4;i++) xs[i] = pL[ti*4+i][k];
    #pragma unroll
    for (int j=0;j<4;j++) ws[j] = wT[k][tj*4+j];
    #pragma unroll
    for (int i=0;i<4;i++)
      #pragma unroll
      for (int j=0;j<4;j++) acc[i][j] += xs[i]*ws[j];
  }
  #pragma unroll
  for (int i=0;i<4;i++)
    #pragma unroll
    for (int j=0;j<4;j++)
      xw[(size_t)(n0+ti*4+i)*64 + tj*4+j] = f2b(acc[i][j]);
}

// ---------------------------------------------------------------------------
// GCN conv: one wave per destination node, CSR gather, 4x unrolled.
__global__ __launch_bounds__(256) void q_gcn(const int* __restrict__ offC,
    const int* __restrict__ csrR, const float* __restrict__ csrW,
    const float* __restrict__ dis, const bf16* __restrict__ xw,
    const float* __restrict__ b1, bf16* __restrict__ x1){
  int n = (blockIdx.x*256 + threadIdx.x) >> 6;
  int f = threadIdx.x & 63;
  float d = dis[n];
  float h = d*d*b2f(xw[(size_t)n*64 + f]);
  int s = offC[n];
  int e = ((n & 511) == 511) ? ((n >> 9) + 1)*EG_ : offC[n+1];
  int j = s;
  for (; j + 3 < e; j += 4){
    int r0 = csrR[j],   r1 = csrR[j+1], r2 = csrR[j+2], r3 = csrR[j+3];
    float w0 = csrW[j], w1 = csrW[j+1], w2 = csrW[j+2], w3 = csrW[j+3];
    float v0 = b2f(xw[(size_t)r0*64 + f]);
    float v1 = b2f(xw[(size_t)r1*64 + f]);
    float v2 = b2f(xw[(size_t)r2*64 + f]);
    float v3 = b2f(xw[(size_t)r3*64 + f]);
    h += w0*v0 + w1*v1 + w2*v2 + w3*v3;
  }
  for (; j < e; ++j) h += csrW[j] * b2f(xw[(size_t)csrR[j]*64 + f]);
  h += b1[f];
  x1[(size_t)n*64 + f] = f2b(h > 0.f ? h : 0.f);
}

// ---------------------------------------------------------------------------
// s1 = softmax(x1 @ Wp1 + bp1): 64 nodes/block, register-tile GEMM.
__global__ __launch_bounds__(256) void q_s1(const bf16* __restrict__ x1,
    const float* __restrict__ Wp1, const float* __restrict__ bp1,
    const float* __restrict__ drow, bf16* __restrict__ s1, float* __restrict__ den){
  __shared__ float xT[64][65];
  __shared__ float wT[64][64];
  __shared__ float denL;
  int t = threadIdx.x;
  int n0 = blockIdx.x*64;
  if (t == 0) denL = 0.f;
  for (int j=t; j<4096; j+=256){
    wT[j>>6][j&63] = Wp1[j];
    xT[j>>6][j&63] = b2f(x1[(size_t)n0*64 + j]);
  }
  __syncthreads();
  int ti = t>>4, tj = t&15;
  float acc[4][4];
  #pragma unroll
  for (int i=0;i<4;i++)
    #pragma unroll
    for (int j=0;j<4;j++) acc[i][j] = 0.f;
  for (int f=0; f<64; ++f){
    float xs[4], ws[4];
    #pragma unroll
    for (int i=0;i<4;i++) xs[i] = xT[ti*4+i][f];
    #pragma unroll
    for (int j=0;j<4;j++) ws[j] = wT[f][tj*4+j];
    #pragma unroll
    for (int i=0;i<4;i++)
      #pragma unroll
      for (int j=0;j<4;j++) acc[i][j] += xs[i]*ws[j];
  }
  {
    float bp[4];
    #pragma unroll
    for (int j=0;j<4;j++) bp[j] = bp1[tj*4+j];
    #pragma unroll
    for (int i=0;i<4;i++)
      #pragma unroll
      for (int j=0;j<4;j++) acc[i][j] += bp[j];
  }
  #pragma unroll
  for (int i=0;i<4;i++){
    float m = fmaxf(fmaxf(acc[i][0],acc[i][1]), fmaxf(acc[i][2],acc[i][3]));
    #pragma unroll
    for (int o=8;o>=1;o>>=1) m = fmaxf(m, __shfl_xor(m, o));
    float e[4]; float ssum = 0.f;
    #pragma unroll
    for (int j=0;j<4;j++){ e[j] = expf(acc[i][j]-m); ssum += e[j]; }
    #pragma unroll
    for (int o=8;o>=1;o>>=1) ssum += __shfl_xor(ssum, o);
    float inv = 1.f/ssum, q = 0.f;
    int n = n0 + ti*4 + i;
    #pragma unroll
    for (int j=0;j<4;j++){
      float sv = e[j]*inv;
      s1[(size_t)n*64 + tj*4 + j] = f2b(sv);
      q += sv*sv;
    }
    #pragma unroll
    for (int o=8;o>=1;o>>=1) q += __shfl_xor(q, o);
    if (tj == 0) atomicAdd(&denL, q * drow[n]);
  }
  __syncthreads();
  if (t == 0) atomicAdd(&den[n0 >> 9], denL);
}

// ---------------------------------------------------------------------------
// U = A @ s1: one wave per row node, CSR(by-row) gather, 4x unrolled.
__global__ __launch_bounds__(256) void q_u(const int* __restrict__ offR,
    const int* __restrict__ csrC, const bf16* __restrict__ s1,
    bf16* __restrict__ U){
  int n = (blockIdx.x*256 + threadIdx.x) >> 6;
  int l = threadIdx.x & 63;
  float u = 0.f;
  int s = offR[n];
  int e = ((n & 511) == 511) ? ((n >> 9) + 1)*EG_ : offR[n+1];
  int j = s;
  for (; j + 3 < e; j += 4){
    int c0 = csrC[j], c1 = csrC[j+1], c2 = csrC[j+2], c3 = csrC[j+3];
    float v0 = b2f(s1[(size_t)c0*64 + l]);
    float v1 = b2f(s1[(size_t)c1*64 + l]);
    float v2 = b2f(s1[(size_t)c2*64 + l]);
    float v3 = b2f(s1[(size_t)c3*64 + l]);
    u += v0 + v1 + v2 + v3;
  }
  for (; j < e; ++j) u += b2f(s1[(size_t)csrC[j]*64 + l]);
  U[(size_t)n*64 + l] = f2b(u);
}

// ---------------------------------------------------------------------------
// q_p3: K-split x2, plain stores into partial buffers p[half].
__global__ __launch_bounds__(256) void q_p3(const bf16* __restrict__ s1,
    const bf16* __restrict__ U, const bf16* __restrict__ x1,
    float* __restrict__ adjPp, float* __restrict__ ssPp, float* __restrict__ X1pp){
  __shared__ float sL[64][64];
  __shared__ float uL[64][64];
  __shared__ float xL[64][64];
  int t = threadIdx.x, blk = blockIdx.x;
  int b = blk >> 1, half = blk & 1;
  int base = b*N_ + half*256;
  int ti = t>>4, tj = t&15;
  float accA[4][4], accS[4][4], accX[4][4];
  #pragma unroll
  for (int i=0;i<4;i++)
    #pragma unroll
    for (int j=0;j<4;j++){ accA[i][j]=0.f; accS[i][j]=0.f; accX[i][j]=0.f; }
  for (int c=0; c<4; ++c){
    __syncthreads();
    for (int j=t; j<4096; j+=256){
      int n = j>>6, q = j&63;
      size_t g = (size_t)(base + c*64 + n)*64 + q;
      sL[n][q] = b2f(s1[g]);
      uL[n][q] = b2f(U [g]);
      xL[n][q] = b2f(x1[g]);
    }
    __syncthreads();
    for (int n=0; n<64; ++n){
      float4 skv = *reinterpret_cast<const float4*>(&sL[n][ti*4]);
      float4 ulv = *reinterpret_cast<const float4*>(&uL[n][tj*4]);
      float4 xlv = *reinterpret_cast<const float4*>(&xL[n][tj*4]);
      float4 slv = *reinterpret_cast<const float4*>(&sL[n][tj*4]);
      float sk[4] = {skv.x, skv.y, skv.z, skv.w};
      float ul[4] = {ulv.x, ulv.y, ulv.z, ulv.w};
      float xl[4] = {xlv.x, xlv.y, xlv.z, xlv.w};
      float sl[4] = {slv.x, slv.y, slv.z, slv.w};
      #pragma unroll
      for (int i=0;i<4;i++)
        #pragma unroll
        for (int j=0;j<4;j++){
          accA[i][j] += sk[i]*ul[j];
          accS[i][j] += sk[i]*sl[j];
          accX[i][j] += sk[i]*xl[j];
        }
    }
  }
  size_t pb = (size_t)half*PHALF + (size_t)b*4096;
  #pragma unroll
  for (int i=0;i<4;i++)
    #pragma unroll
    for (int j=0;j<4;j++){
      size_t o = pb + (ti*4+i)*64 + tj*4+j;
      adjPp[o] = accA[i][j];
      ssPp [o] = accS[i][j];
      X1pp [o] = accX[i][j];
    }
}

// ---------------------------------------------------------------------------
// norm1: sums partials (adjP/ssP in LDS, X1p -> X1n); losses; A2 = degnorm.
__global__ __launch_bounds__(256) void q_norm1(const float* __restrict__ adjPp,
    const float* __restrict__ ssPp, const float* __restrict__ X1pp,
    const float* __restrict__ den, float* __restrict__ A2,
    float* __restrict__ X1n, float* __restrict__ losses){
  __shared__ float aL[4096];
  __shared__ float sL[4096];
  __shared__ float rL[64];
  __shared__ float red[4];
  int b = blockIdx.x, t = threadIdx.x;
  size_t pb = (size_t)b*4096;
  for (int j = t; j < 4096; j += 256){
    aL[j] = adjPp[pb + j] + adjPp[PHALF + pb + j];
    sL[j] = ssPp [pb + j] + ssPp [PHALF + pb + j];
    X1n[pb + j] = X1pp[pb + j] + X1pp[PHALF + pb + j];
  }
  __syncthreads();
  if (t == 0){
    float tr = 0.f;
    for (int k = 0; k < 64; ++k) tr += aL[k*64 + k];
    atomicAdd(&losses[0], -(tr/den[b]) * (1.0f/B_));
  }
  if (t < 64){
    float rs = 0.f;
    for (int l = 0; l < 64; ++l) rs += aL[t*64 + l];
    rs -= aL[t*64 + t];
    rL[t] = 1.f/(sqrtf(rs) + 1e-15f);
  }
  float pp = 0.f;
  for (int j = t; j < 4096; j += 256){ float v = sL[j]; pp += v*v; }
  #pragma unroll
  for (int o = 32; o >= 1; o >>= 1) pp += __shfl_xor(pp, o);
  if ((t & 63) == 0) red[t >> 6] = pp;
  __syncthreads();
  float fro = sqrtf(red[0]+red[1]+red[2]+red[3]);
  __syncthreads();
  float op = 0.f;
  for (int j = t; j < 4096; j += 256){
    int kk = j >> 6, ll = j & 63;
    float v = sL[j]/fro - ((kk==ll) ? 0.125f : 0.f);
    op += v*v;
  }
  #pragma unroll
  for (int o = 32; o >= 1; o >>= 1) op += __shfl_xor(op, o);
  if ((t & 63) == 0) red[t >> 6] = op;
  __syncthreads();
  if (t == 0) atomicAdd(&losses[1], sqrtf(red[0]+red[1]+red[2]+red[3]) * (1.0f/B_));
  for (int j = t; j < 4096; j += 256){
    int kk = j >> 6, ll = j & 63;
    A2[(size_t)b*4096 + j] = (kk==ll) ? 0.f : aL[j]*rL[kk]*rL[ll];
  }
}

// ---------------------------------------------------------------------------
// q_lvl2: FUSED level-2 GCN + pool2 + level-3 GCN per graph. 256 threads,
// register-tiled heavy phases, padded LDS (conflict-free column reads).
__global__ __launch_bounds__(256) void q_lvl2(const float* __restrict__ X1p,
    const float* __restrict__ A2g,
    const float* __restrict__ W2r, const float* __restrict__ b2,
    const float* __restrict__ W2s, const float* __restrict__ Wp2,
    const float* __restrict__ bp2, const float* __restrict__ W3r,
    const float* __restrict__ b3, const float* __restrict__ W3s,
    float* __restrict__ s2f, float* __restrict__ out, float* __restrict__ losses){
  __shared__ float XL[64][65], AL[64][65], AXL[64][65], x2L[64][65];   // 66.6 KB
  __shared__ float s2L[64][33], VL[64][33];                            // 16.9 KB
  __shared__ float adj2L[32][33], ss2L[32][33], A3L[32][33];           // 12.7 KB
  __shared__ float o2L[32][65], GL[32][65];                            // 16.6 KB
  __shared__ float wp2L[64][33];                                       //  8.4 KB
  __shared__ float r2L[32], red[4];
  __shared__ float den2s;
  int t = threadIdx.x, b = blockIdx.x;
  int wv = t>>6, lane = t&63;
  int ti = t>>4, tj = t&15;
  for (int j=t; j<4096; j+=256){
    int n = j>>6, q = j&63;
    XL[n][q] = X1p[(size_t)b*4096 + j];
    AL[n][q] = A2g[(size_t)b*4096 + j];
  }
  for (int j=t; j<2048; j+=256){ int f = j>>5, k = j&31; wp2L[f][k] = Wp2[j]; }
  __syncthreads();
  // AX = A2 @ X1p  (4x4 register tiles)
  {
    float acc[4][4];
    #pragma unroll
    for (int i=0;i<4;i++){ acc[i][0]=0.f; acc[i][1]=0.f; acc[i][2]=0.f; acc[i][3]=0.f; }
    for (int m=0;m<64;++m){
      float av[4], xv[4];
      #pragma unroll
      for (int i=0;i<4;i++) av[i] = AL[ti*4+i][m];
      #pragma unroll
      for (int j=0;j<4;j++) xv[j] = XL[m][tj*4+j];
      #pragma unroll
      for (int i=0;i<4;i++)
        #pragma unroll
        for (int j=0;j<4;j++) acc[i][j] += av[i]*xv[j];
    }
    #pragma unroll
    for (int i=0;i<4;i++)
      #pragma unroll
      for (int j=0;j<4;j++) AXL[ti*4+i][tj*4+j] = acc[i][j];
  }
  __syncthreads();
  // x2 = relu(AXL@W2r + XL@W2s + b2)  (4x4 tiles; W2r/W2s via float4 global)
  {
    float acc[4][4];
    #pragma unroll
    for (int i=0;i<4;i++){ acc[i][0]=0.f; acc[i][1]=0.f; acc[i][2]=0.f; acc[i][3]=0.f; }
    for (int m=0;m<64;++m){
      float a1[4], a2[4];
      #pragma unroll
      for (int i=0;i<4;i++){ a1[i] = AXL[ti*4+i][m]; a2[i] = XL[ti*4+i][m]; }
      float4 wr = *reinterpret_cast<const float4*>(&W2r[m*64 + tj*4]);
      float4 ws = *reinterpret_cast<const float4*>(&W2s[m*64 + tj*4]);
      float wrv[4] = {wr.x, wr.y, wr.z, wr.w};
      float wsv[4] = {ws.x, ws.y, ws.z, ws.w};
      #pragma unroll
      for (int i=0;i<4;i++)
        #pragma unroll
        for (int j=0;j<4;j++) acc[i][j] += a1[i]*wrv[j] + a2[i]*wsv[j];
    }
    float bp[4];
    #pragma unroll
    for (int j=0;j<4;j++) bp[j] = b2[tj*4+j];
    #pragma unroll
    for (int i=0;i<4;i++)
      #pragma unroll
      for (int j=0;j<4;j++){
        float v = acc[i][j] + bp[j];
        x2L[ti*4+i][tj*4+j] = v > 0.f ? v : 0.f;
      }
  }
  __syncthreads();
  // s2 = softmax(x2@Wp2 + bp2) over 32 (duplicated 32-lane halves)
  {
    int k = lane & 31;
    for (int i=0;i<16;i++){
      int n = wv*16+i;
      float lgv = bp2[k];
      for (int f=0; f<64; f++) lgv += x2L[n][f]*wp2L[f][k];
      float m = lgv;
      #pragma unroll
      for (int o=16;o>=1;o>>=1) m = fmaxf(m, __shfl_xor(m, o));
      float p = expf(lgv - m), ssum = p;
      #pragma unroll
      for (int o=16;o>=1;o>>=1) ssum += __shfl_xor(ssum, o);
      float sv = p/ssum;
      s2L[n][k] = sv;
      s2f[(size_t)b*2048 + n*32 + k] = sv;
    }
  }
  __syncthreads();
  // den2 = sum_n ||s2_n||^2 * rowsum(A2[n])
  {
    float part = 0.f;
    if (t < 64){
      float rs = 0.f; for (int m=0;m<64;m++) rs += AL[t][m];
      float q  = 0.f; for (int k2=0;k2<32;k2++){ float s = s2L[t][k2]; q += s*s; }
      part = q*rs;
    }
    #pragma unroll
    for (int o=32;o>=1;o>>=1) part += __shfl_xor(part, o);
    if (t == 0) den2s = part;
  }
  __syncthreads();
  // V = A2 @ s2
  for (int j=0;j<8;j++){
    int idx = t + 256*j; int n = idx>>5, l = idx&31;
    float a = 0.f;
    for (int m=0;m<64;m++) a += AL[n][m]*s2L[m][l];
    VL[n][l] = a;
  }
  __syncthreads();
  // adj2 = s2^T V ; ss2 = s2^T s2
  for (int j=0;j<4;j++){
    int idx = t + 256*j; int k2 = idx>>5, l = idx&31;
    float a = 0.f, c2 = 0.f;
    for (int n=0;n<64;n++){ float s = s2L[n][k2]; a += s*VL[n][l]; c2 += s*s2L[n][l]; }
    adj2L[k2][l] = a; ss2L[k2][l] = c2;
  }
  __syncthreads();
  if (t == 0){
    float tr = 0.f; for (int k2=0;k2<32;k2++) tr += adj2L[k2][k2];
    atomicAdd(&losses[0], -(tr/den2s) * (1.0f/B_));
  }
  if (t < 32){
    float rs = 0.f; for (int l=0;l<32;l++) rs += adj2L[t][l];
    rs -= adj2L[t][t];
    r2L[t] = 1.f/(sqrtf(rs) + 1e-15f);
  }
  // fro2 / ortho2
  {
    float pp = 0.f;
    for (int j=t; j<1024; j+=256){ int k2 = j>>5, l = j&31; float v = ss2L[k2][l]; pp += v*v; }
    #pragma unroll
    for (int o=32;o>=1;o>>=1) pp += __shfl_xor(pp, o);
    if ((t & 63) == 0) red[t >> 6] = pp;
    __syncthreads();
    float fro = sqrtf(red[0]+red[1]+red[2]+red[3]);
    __syncthreads();
    float op = 0.f;
    for (int j=t; j<1024; j+=256){
      int k2 = j>>5, l = j&31;
      float v = ss2L[k2][l]/fro - ((k2==l) ? 0.1767766952966369f : 0.f);
      op += v*v;
    }
    #pragma unroll
    for (int o=32;o>=1;o>>=1) op += __shfl_xor(op, o);
    if ((t & 63) == 0) red[t >> 6] = op;
    __syncthreads();
    if (t == 0) atomicAdd(&losses[1], sqrtf(red[0]+red[1]+red[2]+red[3]) * (1.0f/B_));
  }
  __syncthreads();
  // A3 -> out adj
  for (int j=0;j<4;j++){
    int idx = t + 256*j; int k2 = idx>>5, l = idx&31;
    float v = (k2==l) ? 0.f : adj2L[k2][l]*r2L[k2]*r2L[l];
    A3L[k2][l] = v;
    out[OFF_ADJ + (size_t)b*1024 + idx] = v;
  }
  __syncthreads();
  // o2 = s2^T x2
  for (int j=0;j<8;j++){
    int idx = t + 256*j; int k2 = idx>>6, f = idx&63;
    float a = 0.f;
    for (int n=0;n<64;n++) a += s2L[n][k2]*x2L[n][f];
    o2L[k2][f] = a;
  }
  __syncthreads();
  // G = A3 @ o2
  for (int j=0;j<8;j++){
    int idx = t + 256*j; int n = idx>>6, f = idx&63;
    float a = 0.f;
    for (int m=0;m<32;m++) a += A3L[n][m]*o2L[m][f];
    GL[n][f] = a;
  }
  __syncthreads();
  // x3 = G@W3r + o2@W3s + b3 -> out x  (4x4 tiles; 8x32 thread grid)
  {
    int ti2 = t>>5, tj2 = t&31;         // n tile: ti2*4..+3 (32 rows), o tile: tj2*4..+3 (128 cols)
    float acc[4][4];
    #pragma unroll
    for (int i=0;i<4;i++){ acc[i][0]=0.f; acc[i][1]=0.f; acc[i][2]=0.f; acc[i][3]=0.f; }
    for (int f=0; f<64; ++f){
      float gv[4], ov[4];
      #pragma unroll
      for (int i=0;i<4;i++){ gv[i] = GL[ti2*4+i][f]; ov[i] = o2L[ti2*4+i][f]; }
      float4 wr = *reinterpret_cast<const float4*>(&W3r[f*128 + tj2*4]);
      float4 ws = *reinterpret_cast<const float4*>(&W3s[f*128 + tj2*4]);
      float wrv[4] = {wr.x, wr.y, wr.z, wr.w};
      float wsv[4] = {ws.x, ws.y, ws.z, ws.w};
      #pragma unroll
      for (int i=0;i<4;i++)
        #pragma unroll
        for (int j=0;j<4;j++) acc[i][j] += gv[i]*wrv[j] + ov[i]*wsv[j];
    }
    #pragma unroll
    for (int i=0;i<4;i++)
      #pragma unroll
      for (int j=0;j<4;j++){
        int n = ti2*4+i, o = tj2*4+j;
        out[(size_t)b*4096 + n*128 + o] = acc[i][j] + b3[o];
      }
  }
}

// ---------------------------------------------------------------------------
// agg = s1 @ s2: 8 blocks/graph (64 nodes each), LDS-staged, 4x2 register tile.
__global__ __launch_bounds__(256) void q_agg(const bf16* __restrict__ s1,
    const float* __restrict__ s2, float* __restrict__ out){
  __shared__ float s1L[64][65];
  __shared__ float s2L[64][33];
  int t = threadIdx.x, blk = blockIdx.x;
  int b = blk >> 3, n0 = (blk & 7)*64;
  for (int j=t; j<4096; j+=256){
    int n = j>>6, k = j&63;
    s1L[n][k] = b2f(s1[((size_t)b*N_ + n0 + n)*64 + k]);
  }
  for (int j=t; j<2048; j+=256){
    int k = j>>5, l = j&31;
    s2L[k][l] = s2[(size_t)b*2048 + j];
  }
  __syncthreads();
  int ti = t>>4, tj = t&15;
  float acc[4][2];
  #pragma unroll
  for (int i=0;i<4;i++){ acc[i][0]=0.f; acc[i][1]=0.f; }
  for (int k=0; k<64; ++k){
    float xs[4];
    #pragma unroll
    for (int i=0;i<4;i++) xs[i] = s1L[ti*4+i][k];
    float w0 = s2L[k][tj*2], w1 = s2L[k][tj*2+1];
    #pragma unroll
    for (int i=0;i<4;i++){ acc[i][0] += xs[i]*w0; acc[i][1] += xs[i]*w1; }
  }
  #pragma unroll
  for (int i=0;i<4;i++){
    size_t o = OFF_AGG + ((size_t)b*N_ + n0 + ti*4+i)*32 + tj*2;
    out[o]   = acc[i][0];
    out[o+1] = acc[i][1];
  }
}

// ---------------------------------------------------------------------------
__global__ void q_loss(const float* losses, float* out){
  if (threadIdx.x == 0){
    out[OFF_MC] = losses[0];
    out[OFF_O]  = losses[1];
  }
}

// ===========================================================================
extern "C" void kernel_launch(void* const* d_in, const int* in_sizes, int n_in,
                              void* d_out, int out_size, void* d_ws, size_t ws_size,
                              hipStream_t stream){
  (void)out_size;
  float* out = (float*)d_out;

  static const long long EXP_SIZES[16] = {
    8388608LL, 2097152LL, 1048576LL, 65536LL,
    8192LL, 64LL, 4096LL, 64LL,
    4096LL, 64LL, 4096LL, 2048LL, 32LL,
    8192LL, 128LL, 8192LL };
  if (n_in != 16){ q_sent<<<1,64,0,stream>>>(out, exp2f(36.f)); return; }
  for (int i = 0; i < 16; ++i){
    if ((long long)in_sizes[i] != EXP_SIZES[i]){
      q_sent<<<1,64,0,stream>>>(out, exp2f((float)(37+i))); return;
    }
  }

  const float* pos = (const float*)d_in[0];
  const int*   ei  = (const int*)  d_in[1];
  const float* ea  = (const float*)d_in[2];
  const float* W1  = (const float*)d_in[4];
  const float* b1  = (const float*)d_in[5];
  const float* Wp1 = (const float*)d_in[6];
  const float* bp1 = (const float*)d_in[7];
  const float* W2r = (const float*)d_in[8];
  const float* b2  = (const float*)d_in[9];
  const float* W2s = (const float*)d_in[10];
  const float* Wp2 = (const float*)d_in[11];
  const float* bp2 = (const float*)d_in[12];
  const float* W3r = (const float*)d_in[13];
  const float* b3  = (const float*)d_in[14];
  const float* W3s = (const float*)d_in[15];

  // ---- workspace (~42.1 MB) with lifetime-safe unions
  constexpr size_t MB2 = (size_t)B_*4096*4;     // 2 MB
  char* w = (char*)d_ws;
  float* dis    = (float*)w; w += (size_t)NT_*4;
  float* drow   = (float*)w; w += (size_t)NT_*4;
  float* den    = (float*)w; w += (size_t)B_*4;
  float* losses = (float*)w; w += 64;
  int*   offC   = (int*)  w; w += (size_t)NT_*4;
  int*   offR   = (int*)  w; w += (size_t)NT_*4;
  char*  R1     = w;         w += 2*MB2;
  char*  R2     = w;         w += 2*MB2;
  char*  R3     = w;         w += 2*MB2;
  float* A2n    = (float*)w; w += MB2;
  float* X1n    = (float*)w; w += MB2;
  float* s2     = (float*)w; w += (size_t)B_*2048*4;
  bf16*  xwU    = (bf16*)w;  w += (size_t)NT_*64*2;    // xw, then U
  bf16*  x1     = (bf16*)w;  w += (size_t)NT_*64*2;
  bf16*  s1     = (bf16*)w;  w += (size_t)NT_*64*2;
  size_t need = (size_t)(w - (char*)d_ws);
  if (ws_size < need){ q_sent<<<1,64,0,stream>>>(out, exp2f(20.f)); return; }

  int*   csrR  = (int*)  R1;
  float* csrW  = (float*)R2;
  int*   csrC  = (int*)  R3;
  float* adjPp = (float*)R1;
  float* ssPp  = (float*)R2;
  float* X1pp  = (float*)R3;

  q_init  <<<1,    256, 0, stream>>>(den, losses);
  q_degcsr<<<B_,   256, 0, stream>>>(ei, ea, dis, drow, offC, offR, csrR, csrW, csrC);
  q_xw    <<<NT_/64,256, 0, stream>>>(pos, W1, xwU);
  q_gcn   <<<16384,256, 0, stream>>>(offC, csrR, csrW, dis, xwU, b1, x1);
  q_s1    <<<NT_/64,256, 0, stream>>>(x1, Wp1, bp1, drow, s1, den);
  q_u     <<<16384,256, 0, stream>>>(offR, csrC, s1, xwU);     // xwU := U
  q_p3    <<<B_*2, 256, 0, stream>>>(s1, xwU, x1, adjPp, ssPp, X1pp);
  q_norm1 <<<B_,   256, 0, stream>>>(adjPp, ssPp, X1pp, den, A2n, X1n, losses);
  q_lvl2  <<<B_,   256, 0, stream>>>(X1n, A2n, W2r, b2, W2s, Wp2, bp2,
                                     W3r, b3, W3s, s2, out, losses);
  q_agg   <<<1024, 256, 0, stream>>>(s1, s2, out);
  q_loss  <<<1,     64, 0, stream>>>(losses, out);
}

// Round 22
// 285.983 us; speedup vs baseline: 1.1104x; 1.0463x over previous
//
#include <hip/hip_runtime.h>
#include <hip/hip_bf16.h>

// ============================================================================
// FrameAggregator — ROUND 22:
//  * q_lvl2: ALL phases register-tiled (s2 4x2 w/ 16-lane shfl softmax —
//    removes duplicated logit work; V 4x2; adj2/ss2 2x2; o2,G 2x4).
// Everything else identical to the round-21 passing pipeline.
// ============================================================================

typedef __hip_bfloat16 bf16;
#define DEV static __device__ __forceinline__
DEV float b2f(bf16 x){ return __bfloat162float(x); }
DEV bf16  f2b(float x){ return __float2bfloat16(x); }

constexpr int B_  = 128;
constexpr int N_  = 512;
constexpr int EG_ = 8192;
constexpr int E_  = B_*EG_;     // 1048576
constexpr int NT_ = B_*N_;      // 65536

constexpr size_t OFF_MC  = (size_t)B_*32*128;                 // 524288
constexpr size_t OFF_O   = OFF_MC + 1;
constexpr size_t OFF_AGG = OFF_O + 1;                         // 524290
constexpr size_t OFF_ADJ = OFF_AGG + (size_t)B_*N_*32;        // 2621442

constexpr size_t PHALF = (size_t)B_*4096;                     // partial stride

// ---------------------------------------------------------------------------
__global__ void q_init(float* den, float* losses){
  int i = threadIdx.x;
  if (i < B_) den[i] = 0.f;
  if (i < 2)  losses[i] = 0.f;
}
__global__ void q_sent(float* out, float v){
  if (threadIdx.x == 0) out[0] = v;
}

// ---------------------------------------------------------------------------
// q_degcsr: FUSED deg/drow + CSR build.
__global__ __launch_bounds__(256) void q_degcsr(const int* __restrict__ ei,
    const float* __restrict__ ea, float* __restrict__ dis, float* __restrict__ drow,
    int* __restrict__ offC, int* __restrict__ offR,
    int* __restrict__ csrR, float* __restrict__ csrW, int* __restrict__ csrC){
  __shared__ float degL[N_];
  __shared__ float drL[N_];
  __shared__ int cC[N_], cR[N_];
  int t = threadIdx.x, b = blockIdx.x, base = b*N_, e0 = b*EG_;
  for (int j=t; j<N_; j+=256){ degL[j]=1.0f; drL[j]=0.f; cC[j]=0; cR[j]=0; }
  __syncthreads();
  for (int j=t; j<EG_; j+=256){
    int e = e0 + j;
    int r = ei[e], c = ei[E_+e];
    atomicAdd(&degL[c-base], ea[e]);
    atomicAdd(&drL [r-base], 1.0f);
    atomicAdd(&cC[c-base], 1);
    atomicAdd(&cR[r-base], 1);
  }
  __syncthreads();
  for (int j=t; j<N_; j+=256){
    dis [base+j] = rsqrtf(degL[j]);
    drow[base+j] = drL[j];
  }
  if (t == 0){
    int aC = 0, aR = 0;
    for (int n=0; n<N_; ++n){
      int vc = cC[n], vr = cR[n];
      cC[n] = aC; cR[n] = aR;
      aC += vc; aR += vr;
    }
  }
  __syncthreads();
  for (int j=t; j<N_; j+=256){ offC[base+j] = e0 + cC[j]; offR[base+j] = e0 + cR[j]; }
  __syncthreads();
  for (int j=t; j<EG_; j+=256){
    int e = e0 + j;
    int r = ei[e], c = ei[E_+e];
    float w = rsqrtf(degL[r-base])*ea[e]*rsqrtf(degL[c-base]);
    int p  = atomicAdd(&cC[c-base], 1);
    csrR[e0+p] = r;  csrW[e0+p] = w;
    int p2 = atomicAdd(&cR[r-base], 1);
    csrC[e0+p2] = c;
  }
}

// ---------------------------------------------------------------------------
// xw = pos @ W1: 64-node tiles, LDS-staged pos+W1, 4x4 register tiles.
__global__ __launch_bounds__(256) void q_xw(const float* __restrict__ pos,
    const float* __restrict__ W1, bf16* __restrict__ xw){
  __shared__ float pL[64][129];
  __shared__ float wT[128][64];
  int t = threadIdx.x;
  int n0 = blockIdx.x*64;
  for (int j=t; j<2048; j+=256){
    int n = j >> 5, c4 = j & 31;
    float4 v = *reinterpret_cast<const float4*>(pos + (size_t)(n0+n)*128 + c4*4);
    pL[n][c4*4+0]=v.x; pL[n][c4*4+1]=v.y; pL[n][c4*4+2]=v.z; pL[n][c4*4+3]=v.w;
  }
  for (int j=t; j<8192; j+=256) ((float*)wT)[j] = W1[j];
  __syncthreads();
  int ti = t>>4, tj = t&15;
  float acc[4][4];
  #pragma unroll
  for (int i=0;i<4;i++)
    #pragma unroll
    for (int j=0;j<4;j++) acc[i][j] = 0.f;
  for (int k=0; k<128; ++k){
    float xs[4], ws[4];
    #pragma unroll
    for (int i=0;i<4;i++) xs[i] = pL[ti*4+i][k];
    #pragma unroll
    for (int j=0;j<4;j++) ws[j] = wT[k][tj*4+j];
    #pragma unroll
    for (int i=0;i<4;i++)
      #pragma unroll
      for (int j=0;j<4;j++) acc[i][j] += xs[i]*ws[j];
  }
  #pragma unroll
  for (int i=0;i<4;i++)
    #pragma unroll
    for (int j=0;j<4;j++)
      xw[(size_t)(n0+ti*4+i)*64 + tj*4+j] = f2b(acc[i][j]);
}

// ---------------------------------------------------------------------------
// GCN conv: one wave per destination node, CSR gather, 4x unrolled.
__global__ __launch_bounds__(256) void q_gcn(const int* __restrict__ offC,
    const int* __restrict__ csrR, const float* __restrict__ csrW,
    const float* __restrict__ dis, const bf16* __restrict__ xw,
    const float* __restrict__ b1, bf16* __restrict__ x1){
  int n = (blockIdx.x*256 + threadIdx.x) >> 6;
  int f = threadIdx.x & 63;
  float d = dis[n];
  float h = d*d*b2f(xw[(size_t)n*64 + f]);
  int s = offC[n];
  int e = ((n & 511) == 511) ? ((n >> 9) + 1)*EG_ : offC[n+1];
  int j = s;
  for (; j + 3 < e; j += 4){
    int r0 = csrR[j],   r1 = csrR[j+1], r2 = csrR[j+2], r3 = csrR[j+3];
    float w0 = csrW[j], w1 = csrW[j+1], w2 = csrW[j+2], w3 = csrW[j+3];
    float v0 = b2f(xw[(size_t)r0*64 + f]);
    float v1 = b2f(xw[(size_t)r1*64 + f]);
    float v2 = b2f(xw[(size_t)r2*64 + f]);
    float v3 = b2f(xw[(size_t)r3*64 + f]);
    h += w0*v0 + w1*v1 + w2*v2 + w3*v3;
  }
  for (; j < e; ++j) h += csrW[j] * b2f(xw[(size_t)csrR[j]*64 + f]);
  h += b1[f];
  x1[(size_t)n*64 + f] = f2b(h > 0.f ? h : 0.f);
}

// ---------------------------------------------------------------------------
// s1 = softmax(x1 @ Wp1 + bp1): 64 nodes/block, register-tile GEMM.
__global__ __launch_bounds__(256) void q_s1(const bf16* __restrict__ x1,
    const float* __restrict__ Wp1, const float* __restrict__ bp1,
    const float* __restrict__ drow, bf16* __restrict__ s1, float* __restrict__ den){
  __shared__ float xT[64][65];
  __shared__ float wT[64][64];
  __shared__ float denL;
  int t = threadIdx.x;
  int n0 = blockIdx.x*64;
  if (t == 0) denL = 0.f;
  for (int j=t; j<4096; j+=256){
    wT[j>>6][j&63] = Wp1[j];
    xT[j>>6][j&63] = b2f(x1[(size_t)n0*64 + j]);
  }
  __syncthreads();
  int ti = t>>4, tj = t&15;
  float acc[4][4];
  #pragma unroll
  for (int i=0;i<4;i++)
    #pragma unroll
    for (int j=0;j<4;j++) acc[i][j] = 0.f;
  for (int f=0; f<64; ++f){
    float xs[4], ws[4];
    #pragma unroll
    for (int i=0;i<4;i++) xs[i] = xT[ti*4+i][f];
    #pragma unroll
    for (int j=0;j<4;j++) ws[j] = wT[f][tj*4+j];
    #pragma unroll
    for (int i=0;i<4;i++)
      #pragma unroll
      for (int j=0;j<4;j++) acc[i][j] += xs[i]*ws[j];
  }
  {
    float bp[4];
    #pragma unroll
    for (int j=0;j<4;j++) bp[j] = bp1[tj*4+j];
    #pragma unroll
    for (int i=0;i<4;i++)
      #pragma unroll
      for (int j=0;j<4;j++) acc[i][j] += bp[j];
  }
  #pragma unroll
  for (int i=0;i<4;i++){
    float m = fmaxf(fmaxf(acc[i][0],acc[i][1]), fmaxf(acc[i][2],acc[i][3]));
    #pragma unroll
    for (int o=8;o>=1;o>>=1) m = fmaxf(m, __shfl_xor(m, o));
    float e[4]; float ssum = 0.f;
    #pragma unroll
    for (int j=0;j<4;j++){ e[j] = expf(acc[i][j]-m); ssum += e[j]; }
    #pragma unroll
    for (int o=8;o>=1;o>>=1) ssum += __shfl_xor(ssum, o);
    float inv = 1.f/ssum, q = 0.f;
    int n = n0 + ti*4 + i;
    #pragma unroll
    for (int j=0;j<4;j++){
      float sv = e[j]*inv;
      s1[(size_t)n*64 + tj*4 + j] = f2b(sv);
      q += sv*sv;
    }
    #pragma unroll
    for (int o=8;o>=1;o>>=1) q += __shfl_xor(q, o);
    if (tj == 0) atomicAdd(&denL, q * drow[n]);
  }
  __syncthreads();
  if (t == 0) atomicAdd(&den[n0 >> 9], denL);
}

// ---------------------------------------------------------------------------
// U = A @ s1: one wave per row node, CSR(by-row) gather, 4x unrolled.
__global__ __launch_bounds__(256) void q_u(const int* __restrict__ offR,
    const int* __restrict__ csrC, const bf16* __restrict__ s1,
    bf16* __restrict__ U){
  int n = (blockIdx.x*256 + threadIdx.x) >> 6;
  int l = threadIdx.x & 63;
  float u = 0.f;
  int s = offR[n];
  int e = ((n & 511) == 511) ? ((n >> 9) + 1)*EG_ : offR[n+1];
  int j = s;
  for (; j + 3 < e; j += 4){
    int c0 = csrC[j], c1 = csrC[j+1], c2 = csrC[j+2], c3 = csrC[j+3];
    float v0 = b2f(s1[(size_t)c0*64 + l]);
    float v1 = b2f(s1[(size_t)c1*64 + l]);
    float v2 = b2f(s1[(size_t)c2*64 + l]);
    float v3 = b2f(s1[(size_t)c3*64 + l]);
    u += v0 + v1 + v2 + v3;
  }
  for (; j < e; ++j) u += b2f(s1[(size_t)csrC[j]*64 + l]);
  U[(size_t)n*64 + l] = f2b(u);
}

// ---------------------------------------------------------------------------
// q_p3: K-split x2, plain stores into partial buffers p[half].
__global__ __launch_bounds__(256) void q_p3(const bf16* __restrict__ s1,
    const bf16* __restrict__ U, const bf16* __restrict__ x1,
    float* __restrict__ adjPp, float* __restrict__ ssPp, float* __restrict__ X1pp){
  __shared__ float sL[64][64];
  __shared__ float uL[64][64];
  __shared__ float xL[64][64];
  int t = threadIdx.x, blk = blockIdx.x;
  int b = blk >> 1, half = blk & 1;
  int base = b*N_ + half*256;
  int ti = t>>4, tj = t&15;
  float accA[4][4], accS[4][4], accX[4][4];
  #pragma unroll
  for (int i=0;i<4;i++)
    #pragma unroll
    for (int j=0;j<4;j++){ accA[i][j]=0.f; accS[i][j]=0.f; accX[i][j]=0.f; }
  for (int c=0; c<4; ++c){
    __syncthreads();
    for (int j=t; j<4096; j+=256){
      int n = j>>6, q = j&63;
      size_t g = (size_t)(base + c*64 + n)*64 + q;
      sL[n][q] = b2f(s1[g]);
      uL[n][q] = b2f(U [g]);
      xL[n][q] = b2f(x1[g]);
    }
    __syncthreads();
    for (int n=0; n<64; ++n){
      float4 skv = *reinterpret_cast<const float4*>(&sL[n][ti*4]);
      float4 ulv = *reinterpret_cast<const float4*>(&uL[n][tj*4]);
      float4 xlv = *reinterpret_cast<const float4*>(&xL[n][tj*4]);
      float4 slv = *reinterpret_cast<const float4*>(&sL[n][tj*4]);
      float sk[4] = {skv.x, skv.y, skv.z, skv.w};
      float ul[4] = {ulv.x, ulv.y, ulv.z, ulv.w};
      float xl[4] = {xlv.x, xlv.y, xlv.z, xlv.w};
      float sl[4] = {slv.x, slv.y, slv.z, slv.w};
      #pragma unroll
      for (int i=0;i<4;i++)
        #pragma unroll
        for (int j=0;j<4;j++){
          accA[i][j] += sk[i]*ul[j];
          accS[i][j] += sk[i]*sl[j];
          accX[i][j] += sk[i]*xl[j];
        }
    }
  }
  size_t pb = (size_t)half*PHALF + (size_t)b*4096;
  #pragma unroll
  for (int i=0;i<4;i++)
    #pragma unroll
    for (int j=0;j<4;j++){
      size_t o = pb + (ti*4+i)*64 + tj*4+j;
      adjPp[o] = accA[i][j];
      ssPp [o] = accS[i][j];
      X1pp [o] = accX[i][j];
    }
}

// ---------------------------------------------------------------------------
// norm1: sums partials (adjP/ssP in LDS, X1p -> X1n); losses; A2 = degnorm.
__global__ __launch_bounds__(256) void q_norm1(const float* __restrict__ adjPp,
    const float* __restrict__ ssPp, const float* __restrict__ X1pp,
    const float* __restrict__ den, float* __restrict__ A2,
    float* __restrict__ X1n, float* __restrict__ losses){
  __shared__ float aL[4096];
  __shared__ float sL[4096];
  __shared__ float rL[64];
  __shared__ float red[4];
  int b = blockIdx.x, t = threadIdx.x;
  size_t pb = (size_t)b*4096;
  for (int j = t; j < 4096; j += 256){
    aL[j] = adjPp[pb + j] + adjPp[PHALF + pb + j];
    sL[j] = ssPp [pb + j] + ssPp [PHALF + pb + j];
    X1n[pb + j] = X1pp[pb + j] + X1pp[PHALF + pb + j];
  }
  __syncthreads();
  if (t == 0){
    float tr = 0.f;
    for (int k = 0; k < 64; ++k) tr += aL[k*64 + k];
    atomicAdd(&losses[0], -(tr/den[b]) * (1.0f/B_));
  }
  if (t < 64){
    float rs = 0.f;
    for (int l = 0; l < 64; ++l) rs += aL[t*64 + l];
    rs -= aL[t*64 + t];
    rL[t] = 1.f/(sqrtf(rs) + 1e-15f);
  }
  float pp = 0.f;
  for (int j = t; j < 4096; j += 256){ float v = sL[j]; pp += v*v; }
  #pragma unroll
  for (int o = 32; o >= 1; o >>= 1) pp += __shfl_xor(pp, o);
  if ((t & 63) == 0) red[t >> 6] = pp;
  __syncthreads();
  float fro = sqrtf(red[0]+red[1]+red[2]+red[3]);
  __syncthreads();
  float op = 0.f;
  for (int j = t; j < 4096; j += 256){
    int kk = j >> 6, ll = j & 63;
    float v = sL[j]/fro - ((kk==ll) ? 0.125f : 0.f);
    op += v*v;
  }
  #pragma unroll
  for (int o = 32; o >= 1; o >>= 1) op += __shfl_xor(op, o);
  if ((t & 63) == 0) red[t >> 6] = op;
  __syncthreads();
  if (t == 0) atomicAdd(&losses[1], sqrtf(red[0]+red[1]+red[2]+red[3]) * (1.0f/B_));
  for (int j = t; j < 4096; j += 256){
    int kk = j >> 6, ll = j & 63;
    A2[(size_t)b*4096 + j] = (kk==ll) ? 0.f : aL[j]*rL[kk]*rL[ll];
  }
}

// ---------------------------------------------------------------------------
// q_lvl2: FUSED level-2 GCN + pool2 + level-3 GCN per graph. 256 threads,
// ALL phases register-tiled, padded LDS.
__global__ __launch_bounds__(256) void q_lvl2(const float* __restrict__ X1p,
    const float* __restrict__ A2g,
    const float* __restrict__ W2r, const float* __restrict__ b2,
    const float* __restrict__ W2s, const float* __restrict__ Wp2,
    const float* __restrict__ bp2, const float* __restrict__ W3r,
    const float* __restrict__ b3, const float* __restrict__ W3s,
    float* __restrict__ s2f, float* __restrict__ out, float* __restrict__ losses){
  __shared__ float XL[64][65], AL[64][65], AXL[64][65], x2L[64][65];   // 66.6 KB
  __shared__ float s2L[64][33], VL[64][33];                            // 16.9 KB
  __shared__ float adj2L[32][33], ss2L[32][33], A3L[32][33];           // 12.7 KB
  __shared__ float o2L[32][65], GL[32][65];                            // 16.6 KB
  __shared__ float wp2L[64][33];                                       //  8.4 KB
  __shared__ float r2L[32], red[4];
  __shared__ float den2s;
  int t = threadIdx.x, b = blockIdx.x;
  int ti = t>>4, tj = t&15;
  for (int j=t; j<4096; j+=256){
    int n = j>>6, q = j&63;
    XL[n][q] = X1p[(size_t)b*4096 + j];
    AL[n][q] = A2g[(size_t)b*4096 + j];
  }
  for (int j=t; j<2048; j+=256){ int f = j>>5, k = j&31; wp2L[f][k] = Wp2[j]; }
  __syncthreads();
  // AX = A2 @ X1p  (4x4 register tiles)
  {
    float acc[4][4];
    #pragma unroll
    for (int i=0;i<4;i++){ acc[i][0]=0.f; acc[i][1]=0.f; acc[i][2]=0.f; acc[i][3]=0.f; }
    for (int m=0;m<64;++m){
      float av[4], xv[4];
      #pragma unroll
      for (int i=0;i<4;i++) av[i] = AL[ti*4+i][m];
      #pragma unroll
      for (int j=0;j<4;j++) xv[j] = XL[m][tj*4+j];
      #pragma unroll
      for (int i=0;i<4;i++)
        #pragma unroll
        for (int j=0;j<4;j++) acc[i][j] += av[i]*xv[j];
    }
    #pragma unroll
    for (int i=0;i<4;i++)
      #pragma unroll
      for (int j=0;j<4;j++) AXL[ti*4+i][tj*4+j] = acc[i][j];
  }
  __syncthreads();
  // x2 = relu(AXL@W2r + XL@W2s + b2)  (4x4 tiles; weights via float4 global)
  {
    float acc[4][4];
    #pragma unroll
    for (int i=0;i<4;i++){ acc[i][0]=0.f; acc[i][1]=0.f; acc[i][2]=0.f; acc[i][3]=0.f; }
    for (int m=0;m<64;++m){
      float a1[4], a2[4];
      #pragma unroll
      for (int i=0;i<4;i++){ a1[i] = AXL[ti*4+i][m]; a2[i] = XL[ti*4+i][m]; }
      float4 wr = *reinterpret_cast<const float4*>(&W2r[m*64 + tj*4]);
      float4 ws = *reinterpret_cast<const float4*>(&W2s[m*64 + tj*4]);
      float wrv[4] = {wr.x, wr.y, wr.z, wr.w};
      float wsv[4] = {ws.x, ws.y, ws.z, ws.w};
      #pragma unroll
      for (int i=0;i<4;i++)
        #pragma unroll
        for (int j=0;j<4;j++) acc[i][j] += a1[i]*wrv[j] + a2[i]*wsv[j];
    }
    float bp[4];
    #pragma unroll
    for (int j=0;j<4;j++) bp[j] = b2[tj*4+j];
    #pragma unroll
    for (int i=0;i<4;i++)
      #pragma unroll
      for (int j=0;j<4;j++){
        float v = acc[i][j] + bp[j];
        x2L[ti*4+i][tj*4+j] = v > 0.f ? v : 0.f;
      }
  }
  __syncthreads();
  // s2 = softmax(x2@Wp2 + bp2): 4 nodes x 2 clusters per thread, 16-lane shfl.
  {
    float acc[4][2];
    #pragma unroll
    for (int i=0;i<4;i++){ acc[i][0]=0.f; acc[i][1]=0.f; }
    for (int f=0; f<64; ++f){
      float xv[4];
      #pragma unroll
      for (int i=0;i<4;i++) xv[i] = x2L[ti*4+i][f];
      float w0 = wp2L[f][tj*2], w1 = wp2L[f][tj*2+1];
      #pragma unroll
      for (int i=0;i<4;i++){ acc[i][0] += xv[i]*w0; acc[i][1] += xv[i]*w1; }
    }
    float bq0 = bp2[tj*2], bq1 = bp2[tj*2+1];
    #pragma unroll
    for (int i=0;i<4;i++){
      float l0 = acc[i][0] + bq0, l1 = acc[i][1] + bq1;
      float m = fmaxf(l0, l1);
      #pragma unroll
      for (int o=8;o>=1;o>>=1) m = fmaxf(m, __shfl_xor(m, o));
      float e0 = expf(l0 - m), e1 = expf(l1 - m);
      float ssum = e0 + e1;
      #pragma unroll
      for (int o=8;o>=1;o>>=1) ssum += __shfl_xor(ssum, o);
      float inv = 1.f/ssum;
      float sv0 = e0*inv, sv1 = e1*inv;
      int n = ti*4 + i;
      s2L[n][tj*2]   = sv0;
      s2L[n][tj*2+1] = sv1;
      s2f[(size_t)b*2048 + n*32 + tj*2]   = sv0;
      s2f[(size_t)b*2048 + n*32 + tj*2+1] = sv1;
    }
  }
  __syncthreads();
  // den2 = sum_n ||s2_n||^2 * rowsum(A2[n])
  {
    float part = 0.f;
    if (t < 64){
      float rs = 0.f; for (int m=0;m<64;m++) rs += AL[t][m];
      float q  = 0.f; for (int k2=0;k2<32;k2++){ float s = s2L[t][k2]; q += s*s; }
      part = q*rs;
    }
    #pragma unroll
    for (int o=32;o>=1;o>>=1) part += __shfl_xor(part, o);
    if (t == 0) den2s = part;
  }
  __syncthreads();
  // V = A2 @ s2  (4 rows x 2 cols per thread)
  {
    float acc[4][2];
    #pragma unroll
    for (int i=0;i<4;i++){ acc[i][0]=0.f; acc[i][1]=0.f; }
    for (int m=0;m<64;++m){
      float av[4];
      #pragma unroll
      for (int i=0;i<4;i++) av[i] = AL[ti*4+i][m];
      float s0 = s2L[m][tj*2], s1v = s2L[m][tj*2+1];
      #pragma unroll
      for (int i=0;i<4;i++){ acc[i][0] += av[i]*s0; acc[i][1] += av[i]*s1v; }
    }
    #pragma unroll
    for (int i=0;i<4;i++){
      VL[ti*4+i][tj*2]   = acc[i][0];
      VL[ti*4+i][tj*2+1] = acc[i][1];
    }
  }
  __syncthreads();
  // adj2 = s2^T V ; ss2 = s2^T s2  (2x2 per thread)
  {
    float aA[2][2] = {{0.f,0.f},{0.f,0.f}};
    float aS[2][2] = {{0.f,0.f},{0.f,0.f}};
    for (int n=0;n<64;++n){
      float sk0 = s2L[n][ti*2], sk1 = s2L[n][ti*2+1];
      float vl0 = VL[n][tj*2],  vl1 = VL[n][tj*2+1];
      float sl0 = s2L[n][tj*2], sl1 = s2L[n][tj*2+1];
      aA[0][0] += sk0*vl0; aA[0][1] += sk0*vl1;
      aA[1][0] += sk1*vl0; aA[1][1] += sk1*vl1;
      aS[0][0] += sk0*sl0; aS[0][1] += sk0*sl1;
      aS[1][0] += sk1*sl0; aS[1][1] += sk1*sl1;
    }
    #pragma unroll
    for (int i=0;i<2;i++)
      #pragma unroll
      for (int j=0;j<2;j++){
        adj2L[ti*2+i][tj*2+j] = aA[i][j];
        ss2L [ti*2+i][tj*2+j] = aS[i][j];
      }
  }
  __syncthreads();
  if (t == 0){
    float tr = 0.f; for (int k2=0;k2<32;k2++) tr += adj2L[k2][k2];
    atomicAdd(&losses[0], -(tr/den2s) * (1.0f/B_));
  }
  if (t < 32){
    float rs = 0.f; for (int l=0;l<32;l++) rs += adj2L[t][l];
    rs -= adj2L[t][t];
    r2L[t] = 1.f/(sqrtf(rs) + 1e-15f);
  }
  // fro2 / ortho2
  {
    float pp = 0.f;
    for (int j=t; j<1024; j+=256){ int k2 = j>>5, l = j&31; float v = ss2L[k2][l]; pp += v*v; }
    #pragma unroll
    for (int o=32;o>=1;o>>=1) pp += __shfl_xor(pp, o);
    if ((t & 63) == 0) red[t >> 6] = pp;
    __syncthreads();
    float fro = sqrtf(red[0]+red[1]+red[2]+red[3]);
    __syncthreads();
    float op = 0.f;
    for (int j=t; j<1024; j+=256){
      int k2 = j>>5, l = j&31;
      float v = ss2L[k2][l]/fro - ((k2==l) ? 0.1767766952966369f : 0.f);
      op += v*v;
    }
    #pragma unroll
    for (int o=32;o>=1;o>>=1) op += __shfl_xor(op, o);
    if ((t & 63) == 0) red[t >> 6] = op;
    __syncthreads();
    if (t == 0) atomicAdd(&losses[1], sqrtf(red[0]+red[1]+red[2]+red[3]) * (1.0f/B_));
  }
  __syncthreads();
  // A3 -> out adj
  for (int j=0;j<4;j++){
    int idx = t + 256*j; int k2 = idx>>5, l = idx&31;
    float v = (k2==l) ? 0.f : adj2L[k2][l]*r2L[k2]*r2L[l];
    A3L[k2][l] = v;
    out[OFF_ADJ + (size_t)b*1024 + idx] = v;
  }
  __syncthreads();
  // o2 = s2^T x2  (2 rows x 4 cols per thread)
  {
    float acc[2][4];
    #pragma unroll
    for (int i=0;i<2;i++){ acc[i][0]=0.f; acc[i][1]=0.f; acc[i][2]=0.f; acc[i][3]=0.f; }
    for (int n=0;n<64;++n){
      float sk0 = s2L[n][ti*2], sk1 = s2L[n][ti*2+1];
      float xv[4];
      #pragma unroll
      for (int j=0;j<4;j++) xv[j] = x2L[n][tj*4+j];
      #pragma unroll
      for (int j=0;j<4;j++){ acc[0][j] += sk0*xv[j]; acc[1][j] += sk1*xv[j]; }
    }
    #pragma unroll
    for (int i=0;i<2;i++)
      #pragma unroll
      for (int j=0;j<4;j++) o2L[ti*2+i][tj*4+j] = acc[i][j];
  }
  __syncthreads();
  // G = A3 @ o2  (2 rows x 4 cols per thread, K=32)
  {
    float acc[2][4];
    #pragma unroll
    for (int i=0;i<2;i++){ acc[i][0]=0.f; acc[i][1]=0.f; acc[i][2]=0.f; acc[i][3]=0.f; }
    for (int m=0;m<32;++m){
      float a0 = A3L[ti*2][m], a1 = A3L[ti*2+1][m];
      float ov[4];
      #pragma unroll
      for (int j=0;j<4;j++) ov[j] = o2L[m][tj*4+j];
      #pragma unroll
      for (int j=0;j<4;j++){ acc[0][j] += a0*ov[j]; acc[1][j] += a1*ov[j]; }
    }
    #pragma unroll
    for (int i=0;i<2;i++)
      #pragma unroll
      for (int j=0;j<4;j++) GL[ti*2+i][tj*4+j] = acc[i][j];
  }
  __syncthreads();
  // x3 = G@W3r + o2@W3s + b3 -> out x  (4x4 tiles; 8x32 thread grid)
  {
    int ti2 = t>>5, tj2 = t&31;
    float acc[4][4];
    #pragma unroll
    for (int i=0;i<4;i++){ acc[i][0]=0.f; acc[i][1]=0.f; acc[i][2]=0.f; acc[i][3]=0.f; }
    for (int f=0; f<64; ++f){
      float gv[4], ov[4];
      #pragma unroll
      for (int i=0;i<4;i++){ gv[i] = GL[ti2*4+i][f]; ov[i] = o2L[ti2*4+i][f]; }
      float4 wr = *reinterpret_cast<const float4*>(&W3r[f*128 + tj2*4]);
      float4 ws = *reinterpret_cast<const float4*>(&W3s[f*128 + tj2*4]);
      float wrv[4] = {wr.x, wr.y, wr.z, wr.w};
      float wsv[4] = {ws.x, ws.y, ws.z, ws.w};
      #pragma unroll
      for (int i=0;i<4;i++)
        #pragma unroll
        for (int j=0;j<4;j++) acc[i][j] += gv[i]*wrv[j] + ov[i]*wsv[j];
    }
    #pragma unroll
    for (int i=0;i<4;i++)
      #pragma unroll
      for (int j=0;j<4;j++){
        int n = ti2*4+i, o = tj2*4+j;
        out[(size_t)b*4096 + n*128 + o] = acc[i][j] + b3[o];
      }
  }
}

// ---------------------------------------------------------------------------
// agg = s1 @ s2: 8 blocks/graph (64 nodes each), LDS-staged, 4x2 register tile.
__global__ __launch_bounds__(256) void q_agg(const bf16* __restrict__ s1,
    const float* __restrict__ s2, float* __restrict__ out){
  __shared__ float s1L[64][65];
  __shared__ float s2L[64][33];
  int t = threadIdx.x, blk = blockIdx.x;
  int b = blk >> 3, n0 = (blk & 7)*64;
  for (int j=t; j<4096; j+=256){
    int n = j>>6, k = j&63;
    s1L[n][k] = b2f(s1[((size_t)b*N_ + n0 + n)*64 + k]);
  }
  for (int j=t; j<2048; j+=256){
    int k = j>>5, l = j&31;
    s2L[k][l] = s2[(size_t)b*2048 + j];
  }
  __syncthreads();
  int ti = t>>4, tj = t&15;
  float acc[4][2];
  #pragma unroll
  for (int i=0;i<4;i++){ acc[i][0]=0.f; acc[i][1]=0.f; }
  for (int k=0; k<64; ++k){
    float xs[4];
    #pragma unroll
    for (int i=0;i<4;i++) xs[i] = s1L[ti*4+i][k];
    float w0 = s2L[k][tj*2], w1 = s2L[k][tj*2+1];
    #pragma unroll
    for (int i=0;i<4;i++){ acc[i][0] += xs[i]*w0; acc[i][1] += xs[i]*w1; }
  }
  #pragma unroll
  for (int i=0;i<4;i++){
    size_t o = OFF_AGG + ((size_t)b*N_ + n0 + ti*4+i)*32 + tj*2;
    out[o]   = acc[i][0];
    out[o+1] = acc[i][1];
  }
}

// ---------------------------------------------------------------------------
__global__ void q_loss(const float* losses, float* out){
  if (threadIdx.x == 0){
    out[OFF_MC] = losses[0];
    out[OFF_O]  = losses[1];
  }
}

// ===========================================================================
extern "C" void kernel_launch(void* const* d_in, const int* in_sizes, int n_in,
                              void* d_out, int out_size, void* d_ws, size_t ws_size,
                              hipStream_t stream){
  (void)out_size;
  float* out = (float*)d_out;

  static const long long EXP_SIZES[16] = {
    8388608LL, 2097152LL, 1048576LL, 65536LL,
    8192LL, 64LL, 4096LL, 64LL,
    4096LL, 64LL, 4096LL, 2048LL, 32LL,
    8192LL, 128LL, 8192LL };
  if (n_in != 16){ q_sent<<<1,64,0,stream>>>(out, exp2f(36.f)); return; }
  for (int i = 0; i < 16; ++i){
    if ((long long)in_sizes[i] != EXP_SIZES[i]){
      q_sent<<<1,64,0,stream>>>(out, exp2f((float)(37+i))); return;
    }
  }

  const float* pos = (const float*)d_in[0];
  const int*   ei  = (const int*)  d_in[1];
  const float* ea  = (const float*)d_in[2];
  const float* W1  = (const float*)d_in[4];
  const float* b1  = (const float*)d_in[5];
  const float* Wp1 = (const float*)d_in[6];
  const float* bp1 = (const float*)d_in[7];
  const float* W2r = (const float*)d_in[8];
  const float* b2  = (const float*)d_in[9];
  const float* W2s = (const float*)d_in[10];
  const float* Wp2 = (const float*)d_in[11];
  const float* bp2 = (const float*)d_in[12];
  const float* W3r = (const float*)d_in[13];
  const float* b3  = (const float*)d_in[14];
  const float* W3s = (const float*)d_in[15];

  // ---- workspace (~42.1 MB) with lifetime-safe unions
  constexpr size_t MB2 = (size_t)B_*4096*4;     // 2 MB
  char* w = (char*)d_ws;
  float* dis    = (float*)w; w += (size_t)NT_*4;
  float* drow   = (float*)w; w += (size_t)NT_*4;
  float* den    = (float*)w; w += (size_t)B_*4;
  float* losses = (float*)w; w += 64;
  int*   offC   = (int*)  w; w += (size_t)NT_*4;
  int*   offR   = (int*)  w; w += (size_t)NT_*4;
  char*  R1     = w;         w += 2*MB2;
  char*  R2     = w;         w += 2*MB2;
  char*  R3     = w;         w += 2*MB2;
  float* A2n    = (float*)w; w += MB2;
  float* X1n    = (float*)w; w += MB2;
  float* s2     = (float*)w; w += (size_t)B_*2048*4;
  bf16*  xwU    = (bf16*)w;  w += (size_t)NT_*64*2;    // xw, then U
  bf16*  x1     = (bf16*)w;  w += (size_t)NT_*64*2;
  bf16*  s1     = (bf16*)w;  w += (size_t)NT_*64*2;
  size_t need = (size_t)(w - (char*)d_ws);
  if (ws_size < need){ q_sent<<<1,64,0,stream>>>(out, exp2f(20.f)); return; }

  int*   csrR  = (int*)  R1;
  float* csrW  = (float*)R2;
  int*   csrC  = (int*)  R3;
  float* adjPp = (float*)R1;
  float* ssPp  = (float*)R2;
  float* X1pp  = (float*)R3;

  q_init  <<<1,    256, 0, stream>>>(den, losses);
  q_degcsr<<<B_,   256, 0, stream>>>(ei, ea, dis, drow, offC, offR, csrR, csrW, csrC);
  q_xw    <<<NT_/64,256, 0, stream>>>(pos, W1, xwU);
  q_gcn   <<<16384,256, 0, stream>>>(offC, csrR, csrW, dis, xwU, b1, x1);
  q_s1    <<<NT_/64,256, 0, stream>>>(x1, Wp1, bp1, drow, s1, den);
  q_u     <<<16384,256, 0, stream>>>(offR, csrC, s1, xwU);     // xwU := U
  q_p3    <<<B_*2, 256, 0, stream>>>(s1, xwU, x1, adjPp, ssPp, X1pp);
  q_norm1 <<<B_,   256, 0, stream>>>(adjPp, ssPp, X1pp, den, A2n, X1n, losses);
  q_lvl2  <<<B_,   256, 0, stream>>>(X1n, A2n, W2r, b2, W2s, Wp2, bp2,
                                     W3r, b3, W3s, s2, out, losses);
  q_agg   <<<1024, 256, 0, stream>>>(s1, s2, out);
  q_loss  <<<1,     64, 0, stream>>>(losses, out);
}

// Round 23
// 277.406 us; speedup vs baseline: 1.1447x; 1.0309x over previous
//
#include <hip/hip_runtime.h>
#include <hip/hip_bf16.h>

// ============================================================================
// FrameAggregator — ROUND 23:
//  * q_degcsr: 1024 threads (4 waves/SIMD latency hiding on edge scans)
//  * q_nl2: norm1 FUSED into lvl2 (partial sums staged straight into LDS,
//    in-place degree-normalize; A2n/X1n buffers + one launch eliminated)
// Everything else identical to the round-22 passing pipeline.
// ============================================================================

typedef __hip_bfloat16 bf16;
#define DEV static __device__ __forceinline__
DEV float b2f(bf16 x){ return __bfloat162float(x); }
DEV bf16  f2b(float x){ return __float2bfloat16(x); }

constexpr int B_  = 128;
constexpr int N_  = 512;
constexpr int EG_ = 8192;
constexpr int E_  = B_*EG_;     // 1048576
constexpr int NT_ = B_*N_;      // 65536

constexpr size_t OFF_MC  = (size_t)B_*32*128;                 // 524288
constexpr size_t OFF_O   = OFF_MC + 1;
constexpr size_t OFF_AGG = OFF_O + 1;                         // 524290
constexpr size_t OFF_ADJ = OFF_AGG + (size_t)B_*N_*32;        // 2621442

constexpr size_t PHALF = (size_t)B_*4096;                     // partial stride

// ---------------------------------------------------------------------------
__global__ void q_init(float* den, float* losses){
  int i = threadIdx.x;
  if (i < B_) den[i] = 0.f;
  if (i < 2)  losses[i] = 0.f;
}
__global__ void q_sent(float* out, float v){
  if (threadIdx.x == 0) out[0] = v;
}

// ---------------------------------------------------------------------------
// q_degcsr: FUSED deg/drow + CSR build. 1024 threads for latency hiding.
__global__ __launch_bounds__(1024) void q_degcsr(const int* __restrict__ ei,
    const float* __restrict__ ea, float* __restrict__ dis, float* __restrict__ drow,
    int* __restrict__ offC, int* __restrict__ offR,
    int* __restrict__ csrR, float* __restrict__ csrW, int* __restrict__ csrC){
  __shared__ float degL[N_];
  __shared__ float drL[N_];
  __shared__ int cC[N_], cR[N_];
  int t = threadIdx.x, b = blockIdx.x, base = b*N_, e0 = b*EG_;
  for (int j=t; j<N_; j+=1024){ degL[j]=1.0f; drL[j]=0.f; cC[j]=0; cR[j]=0; }
  __syncthreads();
  for (int j=t; j<EG_; j+=1024){
    int e = e0 + j;
    int r = ei[e], c = ei[E_+e];
    atomicAdd(&degL[c-base], ea[e]);
    atomicAdd(&drL [r-base], 1.0f);
    atomicAdd(&cC[c-base], 1);
    atomicAdd(&cR[r-base], 1);
  }
  __syncthreads();
  for (int j=t; j<N_; j+=1024){
    dis [base+j] = rsqrtf(degL[j]);
    drow[base+j] = drL[j];
  }
  if (t == 0){
    int aC = 0, aR = 0;
    for (int n=0; n<N_; ++n){
      int vc = cC[n], vr = cR[n];
      cC[n] = aC; cR[n] = aR;
      aC += vc; aR += vr;
    }
  }
  __syncthreads();
  for (int j=t; j<N_; j+=1024){ offC[base+j] = e0 + cC[j]; offR[base+j] = e0 + cR[j]; }
  __syncthreads();
  for (int j=t; j<EG_; j+=1024){
    int e = e0 + j;
    int r = ei[e], c = ei[E_+e];
    float w = rsqrtf(degL[r-base])*ea[e]*rsqrtf(degL[c-base]);
    int p  = atomicAdd(&cC[c-base], 1);
    csrR[e0+p] = r;  csrW[e0+p] = w;
    int p2 = atomicAdd(&cR[r-base], 1);
    csrC[e0+p2] = c;
  }
}

// ---------------------------------------------------------------------------
// xw = pos @ W1: 64-node tiles, LDS-staged pos+W1, 4x4 register tiles.
__global__ __launch_bounds__(256) void q_xw(const float* __restrict__ pos,
    const float* __restrict__ W1, bf16* __restrict__ xw){
  __shared__ float pL[64][129];
  __shared__ float wT[128][64];
  int t = threadIdx.x;
  int n0 = blockIdx.x*64;
  for (int j=t; j<2048; j+=256){
    int n = j >> 5, c4 = j & 31;
    float4 v = *reinterpret_cast<const float4*>(pos + (size_t)(n0+n)*128 + c4*4);
    pL[n][c4*4+0]=v.x; pL[n][c4*4+1]=v.y; pL[n][c4*4+2]=v.z; pL[n][c4*4+3]=v.w;
  }
  for (int j=t; j<8192; j+=256) ((float*)wT)[j] = W1[j];
  __syncthreads();
  int ti = t>>4, tj = t&15;
  float acc[4][4];
  #pragma unroll
  for (int i=0;i<4;i++)
    #pragma unroll
    for (int j=0;j<4;j++) acc[i][j] = 0.f;
  for (int k=0; k<128; ++k){
    float xs[4], ws[4];
    #pragma unroll
    for (int i=0;i<4;i++) xs[i] = pL[ti*4+i][k];
    #pragma unroll
    for (int j=0;j<4;j++) ws[j] = wT[k][tj*4+j];
    #pragma unroll
    for (int i=0;i<4;i++)
      #pragma unroll
      for (int j=0;j<4;j++) acc[i][j] += xs[i]*ws[j];
  }
  #pragma unroll
  for (int i=0;i<4;i++)
    #pragma unroll
    for (int j=0;j<4;j++)
      xw[(size_t)(n0+ti*4+i)*64 + tj*4+j] = f2b(acc[i][j]);
}

// ---------------------------------------------------------------------------
// GCN conv: one wave per destination node, CSR gather, 4x unrolled.
__global__ __launch_bounds__(256) void q_gcn(const int* __restrict__ offC,
    const int* __restrict__ csrR, const float* __restrict__ csrW,
    const float* __restrict__ dis, const bf16* __restrict__ xw,
    const float* __restrict__ b1, bf16* __restrict__ x1){
  int n = (blockIdx.x*256 + threadIdx.x) >> 6;
  int f = threadIdx.x & 63;
  float d = dis[n];
  float h = d*d*b2f(xw[(size_t)n*64 + f]);
  int s = offC[n];
  int e = ((n & 511) == 511) ? ((n >> 9) + 1)*EG_ : offC[n+1];
  int j = s;
  for (; j + 3 < e; j += 4){
    int r0 = csrR[j],   r1 = csrR[j+1], r2 = csrR[j+2], r3 = csrR[j+3];
    float w0 = csrW[j], w1 = csrW[j+1], w2 = csrW[j+2], w3 = csrW[j+3];
    float v0 = b2f(xw[(size_t)r0*64 + f]);
    float v1 = b2f(xw[(size_t)r1*64 + f]);
    float v2 = b2f(xw[(size_t)r2*64 + f]);
    float v3 = b2f(xw[(size_t)r3*64 + f]);
    h += w0*v0 + w1*v1 + w2*v2 + w3*v3;
  }
  for (; j < e; ++j) h += csrW[j] * b2f(xw[(size_t)csrR[j]*64 + f]);
  h += b1[f];
  x1[(size_t)n*64 + f] = f2b(h > 0.f ? h : 0.f);
}

// ---------------------------------------------------------------------------
// s1 = softmax(x1 @ Wp1 + bp1): 64 nodes/block, register-tile GEMM.
__global__ __launch_bounds__(256) void q_s1(const bf16* __restrict__ x1,
    const float* __restrict__ Wp1, const float* __restrict__ bp1,
    const float* __restrict__ drow, bf16* __restrict__ s1, float* __restrict__ den){
  __shared__ float xT[64][65];
  __shared__ float wT[64][64];
  __shared__ float denL;
  int t = threadIdx.x;
  int n0 = blockIdx.x*64;
  if (t == 0) denL = 0.f;
  for (int j=t; j<4096; j+=256){
    wT[j>>6][j&63] = Wp1[j];
    xT[j>>6][j&63] = b2f(x1[(size_t)n0*64 + j]);
  }
  __syncthreads();
  int ti = t>>4, tj = t&15;
  float acc[4][4];
  #pragma unroll
  for (int i=0;i<4;i++)
    #pragma unroll
    for (int j=0;j<4;j++) acc[i][j] = 0.f;
  for (int f=0; f<64; ++f){
    float xs[4], ws[4];
    #pragma unroll
    for (int i=0;i<4;i++) xs[i] = xT[ti*4+i][f];
    #pragma unroll
    for (int j=0;j<4;j++) ws[j] = wT[f][tj*4+j];
    #pragma unroll
    for (int i=0;i<4;i++)
      #pragma unroll
      for (int j=0;j<4;j++) acc[i][j] += xs[i]*ws[j];
  }
  {
    float bp[4];
    #pragma unroll
    for (int j=0;j<4;j++) bp[j] = bp1[tj*4+j];
    #pragma unroll
    for (int i=0;i<4;i++)
      #pragma unroll
      for (int j=0;j<4;j++) acc[i][j] += bp[j];
  }
  #pragma unroll
  for (int i=0;i<4;i++){
    float m = fmaxf(fmaxf(acc[i][0],acc[i][1]), fmaxf(acc[i][2],acc[i][3]));
    #pragma unroll
    for (int o=8;o>=1;o>>=1) m = fmaxf(m, __shfl_xor(m, o));
    float e[4]; float ssum = 0.f;
    #pragma unroll
    for (int j=0;j<4;j++){ e[j] = expf(acc[i][j]-m); ssum += e[j]; }
    #pragma unroll
    for (int o=8;o>=1;o>>=1) ssum += __shfl_xor(ssum, o);
    float inv = 1.f/ssum, q = 0.f;
    int n = n0 + ti*4 + i;
    #pragma unroll
    for (int j=0;j<4;j++){
      float sv = e[j]*inv;
      s1[(size_t)n*64 + tj*4 + j] = f2b(sv);
      q += sv*sv;
    }
    #pragma unroll
    for (int o=8;o>=1;o>>=1) q += __shfl_xor(q, o);
    if (tj == 0) atomicAdd(&denL, q * drow[n]);
  }
  __syncthreads();
  if (t == 0) atomicAdd(&den[n0 >> 9], denL);
}

// ---------------------------------------------------------------------------
// U = A @ s1: one wave per row node, CSR(by-row) gather, 4x unrolled.
__global__ __launch_bounds__(256) void q_u(const int* __restrict__ offR,
    const int* __restrict__ csrC, const bf16* __restrict__ s1,
    bf16* __restrict__ U){
  int n = (blockIdx.x*256 + threadIdx.x) >> 6;
  int l = threadIdx.x & 63;
  float u = 0.f;
  int s = offR[n];
  int e = ((n & 511) == 511) ? ((n >> 9) + 1)*EG_ : offR[n+1];
  int j = s;
  for (; j + 3 < e; j += 4){
    int c0 = csrC[j], c1 = csrC[j+1], c2 = csrC[j+2], c3 = csrC[j+3];
    float v0 = b2f(s1[(size_t)c0*64 + l]);
    float v1 = b2f(s1[(size_t)c1*64 + l]);
    float v2 = b2f(s1[(size_t)c2*64 + l]);
    float v3 = b2f(s1[(size_t)c3*64 + l]);
    u += v0 + v1 + v2 + v3;
  }
  for (; j < e; ++j) u += b2f(s1[(size_t)csrC[j]*64 + l]);
  U[(size_t)n*64 + l] = f2b(u);
}

// ---------------------------------------------------------------------------
// q_p3: K-split x2, plain stores into partial buffers p[half].
__global__ __launch_bounds__(256) void q_p3(const bf16* __restrict__ s1,
    const bf16* __restrict__ U, const bf16* __restrict__ x1,
    float* __restrict__ adjPp, float* __restrict__ ssPp, float* __restrict__ X1pp){
  __shared__ float sL[64][64];
  __shared__ float uL[64][64];
  __shared__ float xL[64][64];
  int t = threadIdx.x, blk = blockIdx.x;
  int b = blk >> 1, half = blk & 1;
  int base = b*N_ + half*256;
  int ti = t>>4, tj = t&15;
  float accA[4][4], accS[4][4], accX[4][4];
  #pragma unroll
  for (int i=0;i<4;i++)
    #pragma unroll
    for (int j=0;j<4;j++){ accA[i][j]=0.f; accS[i][j]=0.f; accX[i][j]=0.f; }
  for (int c=0; c<4; ++c){
    __syncthreads();
    for (int j=t; j<4096; j+=256){
      int n = j>>6, q = j&63;
      size_t g = (size_t)(base + c*64 + n)*64 + q;
      sL[n][q] = b2f(s1[g]);
      uL[n][q] = b2f(U [g]);
      xL[n][q] = b2f(x1[g]);
    }
    __syncthreads();
    for (int n=0; n<64; ++n){
      float4 skv = *reinterpret_cast<const float4*>(&sL[n][ti*4]);
      float4 ulv = *reinterpret_cast<const float4*>(&uL[n][tj*4]);
      float4 xlv = *reinterpret_cast<const float4*>(&xL[n][tj*4]);
      float4 slv = *reinterpret_cast<const float4*>(&sL[n][tj*4]);
      float sk[4] = {skv.x, skv.y, skv.z, skv.w};
      float ul[4] = {ulv.x, ulv.y, ulv.z, ulv.w};
      float xl[4] = {xlv.x, xlv.y, xlv.z, xlv.w};
      float sl[4] = {slv.x, slv.y, slv.z, slv.w};
      #pragma unroll
      for (int i=0;i<4;i++)
        #pragma unroll
        for (int j=0;j<4;j++){
          accA[i][j] += sk[i]*ul[j];
          accS[i][j] += sk[i]*sl[j];
          accX[i][j] += sk[i]*xl[j];
        }
    }
  }
  size_t pb = (size_t)half*PHALF + (size_t)b*4096;
  #pragma unroll
  for (int i=0;i<4;i++)
    #pragma unroll
    for (int j=0;j<4;j++){
      size_t o = pb + (ti*4+i)*64 + tj*4+j;
      adjPp[o] = accA[i][j];
      ssPp [o] = accS[i][j];
      X1pp [o] = accX[i][j];
    }
}

// ---------------------------------------------------------------------------
// q_nl2: FUSED norm1 + level-2 GCN + pool2 + level-3 GCN per graph.
// Stages partial sums straight into LDS (ss -> AXL, reused later by AX),
// computes losses + rL, normalizes AL in place, then runs lvl2 phases.
__global__ __launch_bounds__(256) void q_nl2(const float* __restrict__ adjPp,
    const float* __restrict__ ssPp, const float* __restrict__ X1pp,
    const float* __restrict__ den,
    const float* __restrict__ W2r, const float* __restrict__ b2,
    const float* __restrict__ W2s, const float* __restrict__ Wp2,
    const float* __restrict__ bp2, const float* __restrict__ W3r,
    const float* __restrict__ b3, const float* __restrict__ W3s,
    float* __restrict__ s2f, float* __restrict__ out, float* __restrict__ losses){
  __shared__ float XL[64][65], AL[64][65], AXL[64][65], x2L[64][65];
  __shared__ float s2L[64][33], VL[64][33];
  __shared__ float adj2L[32][33], ss2L[32][33], A3L[32][33];
  __shared__ float o2L[32][65], GL[32][65];
  __shared__ float wp2L[64][33];
  __shared__ float rL[64], r2L[32], red[4];
  __shared__ float den2s;
  int t = threadIdx.x, b = blockIdx.x;
  int ti = t>>4, tj = t&15;
  size_t pb = (size_t)b*4096;
  // ---- norm1: sum partials straight into LDS (ss -> AXL) ----
  for (int j=t; j<4096; j+=256){
    int n = j>>6, q = j&63;
    AL [n][q] = adjPp[pb + j] + adjPp[PHALF + pb + j];
    AXL[n][q] = ssPp [pb + j] + ssPp [PHALF + pb + j];
    XL [n][q] = X1pp [pb + j] + X1pp [PHALF + pb + j];
  }
  for (int j=t; j<2048; j+=256){ int f = j>>5, k = j&31; wp2L[f][k] = Wp2[j]; }
  __syncthreads();
  if (t == 0){
    float tr = 0.f;
    for (int k = 0; k < 64; ++k) tr += AL[k][k];
    atomicAdd(&losses[0], -(tr/den[b]) * (1.0f/B_));
  }
  if (t < 64){
    float rs = 0.f;
    for (int l = 0; l < 64; ++l) rs += AL[t][l];
    rs -= AL[t][t];
    rL[t] = 1.f/(sqrtf(rs) + 1e-15f);
  }
  float pp1 = 0.f;
  for (int j = t; j < 4096; j += 256){ float v = AXL[j>>6][j&63]; pp1 += v*v; }
  #pragma unroll
  for (int o = 32; o >= 1; o >>= 1) pp1 += __shfl_xor(pp1, o);
  if ((t & 63) == 0) red[t >> 6] = pp1;
  __syncthreads();                               // publishes red AND rL
  float fro1 = sqrtf(red[0]+red[1]+red[2]+red[3]);
  __syncthreads();
  float op1 = 0.f;
  for (int j = t; j < 4096; j += 256){
    int kk = j >> 6, ll = j & 63;
    float v = AXL[kk][ll]/fro1 - ((kk==ll) ? 0.125f : 0.f);   // I/sqrt(64)
    op1 += v*v;
  }
  #pragma unroll
  for (int o = 32; o >= 1; o >>= 1) op1 += __shfl_xor(op1, o);
  if ((t & 63) == 0) red[t >> 6] = op1;
  __syncthreads();
  if (t == 0) atomicAdd(&losses[1], sqrtf(red[0]+red[1]+red[2]+red[3]) * (1.0f/B_));
  // A2 in place on AL (rL published; original AL values no longer needed)
  for (int j = t; j < 4096; j += 256){
    int kk = j >> 6, ll = j & 63;
    AL[kk][ll] = (kk==ll) ? 0.f : AL[kk][ll]*rL[kk]*rL[ll];
  }
  __syncthreads();
  // ---- lvl2 phases (AL = A2, XL = X1n) ----
  // AX = A2 @ X1p  (4x4 register tiles; overwrites AXL)
  {
    float acc[4][4];
    #pragma unroll
    for (int i=0;i<4;i++){ acc[i][0]=0.f; acc[i][1]=0.f; acc[i][2]=0.f; acc[i][3]=0.f; }
    for (int m=0;m<64;++m){
      float av[4], xv[4];
      #pragma unroll
      for (int i=0;i<4;i++) av[i] = AL[ti*4+i][m];
      #pragma unroll
      for (int j=0;j<4;j++) xv[j] = XL[m][tj*4+j];
      #pragma unroll
      for (int i=0;i<4;i++)
        #pragma unroll
        for (int j=0;j<4;j++) acc[i][j] += av[i]*xv[j];
    }
    __syncthreads();                 // all reads of AXL-as-ss done above
    #pragma unroll
    for (int i=0;i<4;i++)
      #pragma unroll
      for (int j=0;j<4;j++) AXL[ti*4+i][tj*4+j] = acc[i][j];
  }
  __syncthreads();
  // x2 = relu(AXL@W2r + XL@W2s + b2)
  {
    float acc[4][4];
    #pragma unroll
    for (int i=0;i<4;i++){ acc[i][0]=0.f; acc[i][1]=0.f; acc[i][2]=0.f; acc[i][3]=0.f; }
    for (int m=0;m<64;++m){
      float a1[4], a2[4];
      #pragma unroll
      for (int i=0;i<4;i++){ a1[i] = AXL[ti*4+i][m]; a2[i] = XL[ti*4+i][m]; }
      float4 wr = *reinterpret_cast<const float4*>(&W2r[m*64 + tj*4]);
      float4 ws = *reinterpret_cast<const float4*>(&W2s[m*64 + tj*4]);
      float wrv[4] = {wr.x, wr.y, wr.z, wr.w};
      float wsv[4] = {ws.x, ws.y, ws.z, ws.w};
      #pragma unroll
      for (int i=0;i<4;i++)
        #pragma unroll
        for (int j=0;j<4;j++) acc[i][j] += a1[i]*wrv[j] + a2[i]*wsv[j];
    }
    float bp[4];
    #pragma unroll
    for (int j=0;j<4;j++) bp[j] = b2[tj*4+j];
    #pragma unroll
    for (int i=0;i<4;i++)
      #pragma unroll
      for (int j=0;j<4;j++){
        float v = acc[i][j] + bp[j];
        x2L[ti*4+i][tj*4+j] = v > 0.f ? v : 0.f;
      }
  }
  __syncthreads();
  // s2 = softmax(x2@Wp2 + bp2): 4 nodes x 2 clusters per thread.
  {
    float acc[4][2];
    #pragma unroll
    for (int i=0;i<4;i++){ acc[i][0]=0.f; acc[i][1]=0.f; }
    for (int f=0; f<64; ++f){
      float xv[4];
      #pragma unroll
      for (int i=0;i<4;i++) xv[i] = x2L[ti*4+i][f];
      float w0 = wp2L[f][tj*2], w1 = wp2L[f][tj*2+1];
      #pragma unroll
      for (int i=0;i<4;i++){ acc[i][0] += xv[i]*w0; acc[i][1] += xv[i]*w1; }
    }
    float bq0 = bp2[tj*2], bq1 = bp2[tj*2+1];
    #pragma unroll
    for (int i=0;i<4;i++){
      float l0 = acc[i][0] + bq0, l1 = acc[i][1] + bq1;
      float m = fmaxf(l0, l1);
      #pragma unroll
      for (int o=8;o>=1;o>>=1) m = fmaxf(m, __shfl_xor(m, o));
      float e0 = expf(l0 - m), e1 = expf(l1 - m);
      float ssum = e0 + e1;
      #pragma unroll
      for (int o=8;o>=1;o>>=1) ssum += __shfl_xor(ssum, o);
      float inv = 1.f/ssum;
      float sv0 = e0*inv, sv1 = e1*inv;
      int n = ti*4 + i;
      s2L[n][tj*2]   = sv0;
      s2L[n][tj*2+1] = sv1;
      s2f[(size_t)b*2048 + n*32 + tj*2]   = sv0;
      s2f[(size_t)b*2048 + n*32 + tj*2+1] = sv1;
    }
  }
  __syncthreads();
  // den2 = sum_n ||s2_n||^2 * rowsum(A2[n])
  {
    float part = 0.f;
    if (t < 64){
      float rs = 0.f; for (int m=0;m<64;m++) rs += AL[t][m];
      float q  = 0.f; for (int k2=0;k2<32;k2++){ float s = s2L[t][k2]; q += s*s; }
      part = q*rs;
    }
    #pragma unroll
    for (int o=32;o>=1;o>>=1) part += __shfl_xor(part, o);
    if (t == 0) den2s = part;
  }
  __syncthreads();
  // V = A2 @ s2  (4 rows x 2 cols per thread)
  {
    float acc[4][2];
    #pragma unroll
    for (int i=0;i<4;i++){ acc[i][0]=0.f; acc[i][1]=0.f; }
    for (int m=0;m<64;++m){
      float av[4];
      #pragma unroll
      for (int i=0;i<4;i++) av[i] = AL[ti*4+i][m];
      float s0 = s2L[m][tj*2], s1v = s2L[m][tj*2+1];
      #pragma unroll
      for (int i=0;i<4;i++){ acc[i][0] += av[i]*s0; acc[i][1] += av[i]*s1v; }
    }
    #pragma unroll
    for (int i=0;i<4;i++){
      VL[ti*4+i][tj*2]   = acc[i][0];
      VL[ti*4+i][tj*2+1] = acc[i][1];
    }
  }
  __syncthreads();
  // adj2 = s2^T V ; ss2 = s2^T s2  (2x2 per thread)
  {
    float aA[2][2] = {{0.f,0.f},{0.f,0.f}};
    float aS[2][2] = {{0.f,0.f},{0.f,0.f}};
    for (int n=0;n<64;++n){
      float sk0 = s2L[n][ti*2], sk1 = s2L[n][ti*2+1];
      float vl0 = VL[n][tj*2],  vl1 = VL[n][tj*2+1];
      float sl0 = s2L[n][tj*2], sl1 = s2L[n][tj*2+1];
      aA[0][0] += sk0*vl0; aA[0][1] += sk0*vl1;
      aA[1][0] += sk1*vl0; aA[1][1] += sk1*vl1;
      aS[0][0] += sk0*sl0; aS[0][1] += sk0*sl1;
      aS[1][0] += sk1*sl0; aS[1][1] += sk1*sl1;
    }
    #pragma unroll
    for (int i=0;i<2;i++)
      #pragma unroll
      for (int j=0;j<2;j++){
        adj2L[ti*2+i][tj*2+j] = aA[i][j];
        ss2L [ti*2+i][tj*2+j] = aS[i][j];
      }
  }
  __syncthreads();
  if (t == 0){
    float tr = 0.f; for (int k2=0;k2<32;k2++) tr += adj2L[k2][k2];
    atomicAdd(&losses[0], -(tr/den2s) * (1.0f/B_));
  }
  if (t < 32){
    float rs = 0.f; for (int l=0;l<32;l++) rs += adj2L[t][l];
    rs -= adj2L[t][t];
    r2L[t] = 1.f/(sqrtf(rs) + 1e-15f);
  }
  // fro2 / ortho2
  {
    float pp = 0.f;
    for (int j=t; j<1024; j+=256){ int k2 = j>>5, l = j&31; float v = ss2L[k2][l]; pp += v*v; }
    #pragma unroll
    for (int o=32;o>=1;o>>=1) pp += __shfl_xor(pp, o);
    if ((t & 63) == 0) red[t >> 6] = pp;
    __syncthreads();
    float fro = sqrtf(red[0]+red[1]+red[2]+red[3]);
    __syncthreads();
    float op = 0.f;
    for (int j=t; j<1024; j+=256){
      int k2 = j>>5, l = j&31;
      float v = ss2L[k2][l]/fro - ((k2==l) ? 0.1767766952966369f : 0.f);
      op += v*v;
    }
    #pragma unroll
    for (int o=32;o>=1;o>>=1) op += __shfl_xor(op, o);
    if ((t & 63) == 0) red[t >> 6] = op;
    __syncthreads();
    if (t == 0) atomicAdd(&losses[1], sqrtf(red[0]+red[1]+red[2]+red[3]) * (1.0f/B_));
  }
  __syncthreads();
  // A3 -> out adj
  for (int j=0;j<4;j++){
    int idx = t + 256*j; int k2 = idx>>5, l = idx&31;
    float v = (k2==l) ? 0.f : adj2L[k2][l]*r2L[k2]*r2L[l];
    A3L[k2][l] = v;
    out[OFF_ADJ + (size_t)b*1024 + idx] = v;
  }
  __syncthreads();
  // o2 = s2^T x2  (2 rows x 4 cols per thread)
  {
    float acc[2][4];
    #pragma unroll
    for (int i=0;i<2;i++){ acc[i][0]=0.f; acc[i][1]=0.f; acc[i][2]=0.f; acc[i][3]=0.f; }
    for (int n=0;n<64;++n){
      float sk0 = s2L[n][ti*2], sk1 = s2L[n][ti*2+1];
      float xv[4];
      #pragma unroll
      for (int j=0;j<4;j++) xv[j] = x2L[n][tj*4+j];
      #pragma unroll
      for (int j=0;j<4;j++){ acc[0][j] += sk0*xv[j]; acc[1][j] += sk1*xv[j]; }
    }
    #pragma unroll
    for (int i=0;i<2;i++)
      #pragma unroll
      for (int j=0;j<4;j++) o2L[ti*2+i][tj*4+j] = acc[i][j];
  }
  __syncthreads();
  // G = A3 @ o2  (2 rows x 4 cols per thread, K=32)
  {
    float acc[2][4];
    #pragma unroll
    for (int i=0;i<2;i++){ acc[i][0]=0.f; acc[i][1]=0.f; acc[i][2]=0.f; acc[i][3]=0.f; }
    for (int m=0;m<32;++m){
      float a0 = A3L[ti*2][m], a1 = A3L[ti*2+1][m];
      float ov[4];
      #pragma unroll
      for (int j=0;j<4;j++) ov[j] = o2L[m][tj*4+j];
      #pragma unroll
      for (int j=0;j<4;j++){ acc[0][j] += a0*ov[j]; acc[1][j] += a1*ov[j]; }
    }
    #pragma unroll
    for (int i=0;i<2;i++)
      #pragma unroll
      for (int j=0;j<4;j++) GL[ti*2+i][tj*4+j] = acc[i][j];
  }
  __syncthreads();
  // x3 = G@W3r + o2@W3s + b3 -> out x  (4x4 tiles; 8x32 thread grid)
  {
    int ti2 = t>>5, tj2 = t&31;
    float acc[4][4];
    #pragma unroll
    for (int i=0;i<4;i++){ acc[i][0]=0.f; acc[i][1]=0.f; acc[i][2]=0.f; acc[i][3]=0.f; }
    for (int f=0; f<64; ++f){
      float gv[4], ov[4];
      #pragma unroll
      for (int i=0;i<4;i++){ gv[i] = GL[ti2*4+i][f]; ov[i] = o2L[ti2*4+i][f]; }
      float4 wr = *reinterpret_cast<const float4*>(&W3r[f*128 + tj2*4]);
      float4 ws = *reinterpret_cast<const float4*>(&W3s[f*128 + tj2*4]);
      float wrv[4] = {wr.x, wr.y, wr.z, wr.w};
      float wsv[4] = {ws.x, ws.y, ws.z, ws.w};
      #pragma unroll
      for (int i=0;i<4;i++)
        #pragma unroll
        for (int j=0;j<4;j++) acc[i][j] += gv[i]*wrv[j] + ov[i]*wsv[j];
    }
    #pragma unroll
    for (int i=0;i<4;i++)
      #pragma unroll
      for (int j=0;j<4;j++){
        int n = ti2*4+i, o = tj2*4+j;
        out[(size_t)b*4096 + n*128 + o] = acc[i][j] + b3[o];
      }
  }
}

// ---------------------------------------------------------------------------
// agg = s1 @ s2: 8 blocks/graph (64 nodes each), LDS-staged, 4x2 register tile.
__global__ __launch_bounds__(256) void q_agg(const bf16* __restrict__ s1,
    const float* __restrict__ s2, float* __restrict__ out){
  __shared__ float s1L[64][65];
  __shared__ float s2L[64][33];
  int t = threadIdx.x, blk = blockIdx.x;
  int b = blk >> 3, n0 = (blk & 7)*64;
  for (int j=t; j<4096; j+=256){
    int n = j>>6, k = j&63;
    s1L[n][k] = b2f(s1[((size_t)b*N_ + n0 + n)*64 + k]);
  }
  for (int j=t; j<2048; j+=256){
    int k = j>>5, l = j&31;
    s2L[k][l] = s2[(size_t)b*2048 + j];
  }
  __syncthreads();
  int ti = t>>4, tj = t&15;
  float acc[4][2];
  #pragma unroll
  for (int i=0;i<4;i++){ acc[i][0]=0.f; acc[i][1]=0.f; }
  for (int k=0; k<64; ++k){
    float xs[4];
    #pragma unroll
    for (int i=0;i<4;i++) xs[i] = s1L[ti*4+i][k];
    float w0 = s2L[k][tj*2], w1 = s2L[k][tj*2+1];
    #pragma unroll
    for (int i=0;i<4;i++){ acc[i][0] += xs[i]*w0; acc[i][1] += xs[i]*w1; }
  }
  #pragma unroll
  for (int i=0;i<4;i++){
    size_t o = OFF_AGG + ((size_t)b*N_ + n0 + ti*4+i)*32 + tj*2;
    out[o]   = acc[i][0];
    out[o+1] = acc[i][1];
  }
}

// ---------------------------------------------------------------------------
__global__ void q_loss(const float* losses, float* out){
  if (threadIdx.x == 0){
    out[OFF_MC] = losses[0];
    out[OFF_O]  = losses[1];
  }
}

// ===========================================================================
extern "C" void kernel_launch(void* const* d_in, const int* in_sizes, int n_in,
                              void* d_out, int out_size, void* d_ws, size_t ws_size,
                              hipStream_t stream){
  (void)out_size;
  float* out = (float*)d_out;

  static const long long EXP_SIZES[16] = {
    8388608LL, 2097152LL, 1048576LL, 65536LL,
    8192LL, 64LL, 4096LL, 64LL,
    4096LL, 64LL, 4096LL, 2048LL, 32LL,
    8192LL, 128LL, 8192LL };
  if (n_in != 16){ q_sent<<<1,64,0,stream>>>(out, exp2f(36.f)); return; }
  for (int i = 0; i < 16; ++i){
    if ((long long)in_sizes[i] != EXP_SIZES[i]){
      q_sent<<<1,64,0,stream>>>(out, exp2f((float)(37+i))); return;
    }
  }

  const float* pos = (const float*)d_in[0];
  const int*   ei  = (const int*)  d_in[1];
  const float* ea  = (const float*)d_in[2];
  const float* W1  = (const float*)d_in[4];
  const float* b1  = (const float*)d_in[5];
  const float* Wp1 = (const float*)d_in[6];
  const float* bp1 = (const float*)d_in[7];
  const float* W2r = (const float*)d_in[8];
  const float* b2  = (const float*)d_in[9];
  const float* W2s = (const float*)d_in[10];
  const float* Wp2 = (const float*)d_in[11];
  const float* bp2 = (const float*)d_in[12];
  const float* W3r = (const float*)d_in[13];
  const float* b3  = (const float*)d_in[14];
  const float* W3s = (const float*)d_in[15];

  // ---- workspace (~38 MB) with lifetime-safe unions
  constexpr size_t MB2 = (size_t)B_*4096*4;     // 2 MB
  char* w = (char*)d_ws;
  float* dis    = (float*)w; w += (size_t)NT_*4;
  float* drow   = (float*)w; w += (size_t)NT_*4;
  float* den    = (float*)w; w += (size_t)B_*4;
  float* losses = (float*)w; w += 64;
  int*   offC   = (int*)  w; w += (size_t)NT_*4;
  int*   offR   = (int*)  w; w += (size_t)NT_*4;
  char*  R1     = w;         w += 2*MB2;
  char*  R2     = w;         w += 2*MB2;
  char*  R3     = w;         w += 2*MB2;
  float* s2     = (float*)w; w += (size_t)B_*2048*4;
  bf16*  xwU    = (bf16*)w;  w += (size_t)NT_*64*2;    // xw, then U
  bf16*  x1     = (bf16*)w;  w += (size_t)NT_*64*2;
  bf16*  s1     = (bf16*)w;  w += (size_t)NT_*64*2;
  size_t need = (size_t)(w - (char*)d_ws);
  if (ws_size < need){ q_sent<<<1,64,0,stream>>>(out, exp2f(20.f)); return; }

  int*   csrR  = (int*)  R1;
  float* csrW  = (float*)R2;
  int*   csrC  = (int*)  R3;
  float* adjPp = (float*)R1;
  float* ssPp  = (float*)R2;
  float* X1pp  = (float*)R3;

  q_init  <<<1,    256, 0, stream>>>(den, losses);
  q_degcsr<<<B_,  1024, 0, stream>>>(ei, ea, dis, drow, offC, offR, csrR, csrW, csrC);
  q_xw    <<<NT_/64,256, 0, stream>>>(pos, W1, xwU);
  q_gcn   <<<16384,256, 0, stream>>>(offC, csrR, csrW, dis, xwU, b1, x1);
  q_s1    <<<NT_/64,256, 0, stream>>>(x1, Wp1, bp1, drow, s1, den);
  q_u     <<<16384,256, 0, stream>>>(offR, csrC, s1, xwU);     // xwU := U
  q_p3    <<<B_*2, 256, 0, stream>>>(s1, xwU, x1, adjPp, ssPp, X1pp);
  q_nl2   <<<B_,   256, 0, stream>>>(adjPp, ssPp, X1pp, den, W2r, b2, W2s,
                                     Wp2, bp2, W3r, b3, W3s, s2, out, losses);
  q_agg   <<<1024, 256, 0, stream>>>(s1, s2, out);
  q_loss  <<<1,     64, 0, stream>>>(losses, out);
}